// Round 12
// baseline (1677.054 us; speedup 1.0000x reference)
//
#include <hip/hip_runtime.h>

typedef _Float16 f16;
typedef _Float16 f16x8 __attribute__((ext_vector_type(8)));
typedef _Float16 f16x4 __attribute__((ext_vector_type(4)));
typedef float f32x4 __attribute__((ext_vector_type(4)));

#define GLD(g, l) __builtin_amdgcn_global_load_lds( \
    (const __attribute__((address_space(1))) void*)(g), \
    (__attribute__((address_space(3))) void*)(l), 16, 0, 0)

enum { MZ0, MVN, MU, MUL, MQP, MG, ME, MWP };

struct Ep {
  const f16 *Ah, *Bh, *Bl;       // primary: A (1 plane) x B (2 planes)
  const f16 *A2, *B2;            // VNEW extra pass: r2h @ E32
  const f16 *Ch, *Dh, *Dl;       // QP p-half: ph @ {Wh, Wl}
  f16 *o0h, *o0l, *o1h, *o1l, *o2h, *o2l;
  f16 *ov, *op;                  // single-plane outs (v, p)
  float* of;
  const f16 *x0h, *x0l, *x2h, *x2l, *x3h, *x3l;
  const f16* x1s;                // single-plane read (v)
  const float* rf0;
  const float *w0, *w1, *w2, *w3;
  const float *bias, *bias2;
  float sAi, sSi, sPi, sO, sO2;
  int Mh, dos2;
  size_t zA, zB, zO;
};

// ---- vectorized epilogue helpers (8-elem chunks) ----
__device__ __forceinline__ void ld_pair8(const f16* h, const f16* l, size_t i, float s, float* o) {
  const f16x8 hv = *(const f16x8*)(h + i);
  const f16x8 lv = *(const f16x8*)(l + i);
#pragma unroll
  for (int e = 0; e < 8; e++) o[e] = ((float)hv[e] + (float)lv[e]) * s;
}
__device__ __forceinline__ void ld_s8(const f16* p, size_t i, float s, float* o) {
  const f16x8 hv = *(const f16x8*)(p + i);
#pragma unroll
  for (int e = 0; e < 8; e++) o[e] = (float)hv[e] * s;
}
__device__ __forceinline__ void ld_f8(const float* p, size_t i, float* o) {
  const float4 a = *(const float4*)(p + i);
  const float4 b = *(const float4*)(p + i + 4);
  o[0] = a.x; o[1] = a.y; o[2] = a.z; o[3] = a.w;
  o[4] = b.x; o[5] = b.y; o[6] = b.z; o[7] = b.w;
}
__device__ __forceinline__ void st_pair8(f16* h, f16* l, size_t i, const float* v, float s) {
  f16x8 hv, lv;
#pragma unroll
  for (int e = 0; e < 8; e++) {
    const float x = v[e] * s;
    const f16 hi = (f16)x;
    hv[e] = hi;
    lv[e] = (f16)(x - (float)hi);
  }
  *(f16x8*)(h + i) = hv;
  *(f16x8*)(l + i) = lv;
}
__device__ __forceinline__ void st_s8(f16* p, size_t i, const float* v, float s) {
  f16x8 hv;
#pragma unroll
  for (int e = 0; e < 8; e++) hv[e] = (f16)(v[e] * s);
  *(f16x8*)(p + i) = hv;
}
__device__ __forceinline__ void st_f8(float* p, size_t i, const float* v) {
  *(float4*)(p + i) = make_float4(v[0], v[1], v[2], v[3]);
  *(float4*)(p + i + 4) = make_float4(v[4], v[5], v[6], v[7]);
}

// C = sum_passes A_p @ B_p^T; 128x128 tiles, BK=32, 4 waves (2x2).
// NP=1 {A@B0}; NP=2 {A@B0, A@B1}; NP=3 (VNEW) {.., A2@B2}. A single-plane, B split.
// Rotated K-loop (stage next step under MFMA) + chunked XCD swizzle.
// NP>=2: LDS-staged epilogue -> each thread owns 32 consecutive cols of one row,
// all state streams as f16x8/float4 vector ops (bit-identical math to scalar path).
template <int MODE>
__global__ __launch_bounds__(256, 2) void gk(Ep ep) {
  constexpr int NP = (MODE == MVN) ? 3
                   : (MODE == MG || MODE == ME || MODE == MWP) ? 1 : 2;
  constexpr int STGB = (NP == 3 ? 5 : NP == 2 ? 3 : 2) * 8192;  // staging bytes
  constexpr int EPIB = 64 * 132 * 4;                            // 33792
  constexpr int SMB = (NP >= 2 && EPIB > STGB) ? EPIB : STGB;
  __shared__ char SMEM[SMB] __attribute__((aligned(16)));
  f16* SA0 = (f16*)SMEM;
  f16* SB0 = SA0 + 4096;
  f16* SB1 = SB0 + 4096;       // NP>=2
  f16* SA2 = SB1 + 4096;       // NP==3
  f16* SB2 = SA2 + 4096;       // NP==3
  const int tid = threadIdx.x;
  const int w = tid >> 6, lane = tid & 63;
  const unsigned nb = gridDim.x;
  const unsigned bid = blockIdx.x;
  const unsigned swz = (bid & 7) * (nb >> 3) + (bid >> 3);  // bijective, nb%8==0
  const int tn = (int)(swz & 7) * 128;
  const int tm = (int)(swz >> 3) * 128;
  const int ly = blockIdx.y;
  const size_t zoA = (size_t)ly * ep.zA;
  const size_t zoB = (size_t)ly * ep.zB;
  const size_t zoO = (size_t)ly * ep.zO;

  const bool half2 = (MODE == MQP) && (tm >= ep.Mh);
  const int tmr = half2 ? tm - ep.Mh : tm;

  const f16* pA0 = half2 ? ep.Ch : ep.Ah;
  const f16* pB0 = half2 ? ep.Dh : ep.Bh;
  const f16* pB1 = half2 ? ep.Dl : ep.Bl;

  const int srow = w * 16 + (lane >> 2);
  const int scol = (lane & 3) * 8;
  const size_t aoff = zoA + (size_t)(tmr + srow) * 1024 + scol;
  const size_t boff = zoB + (size_t)(tn + srow) * 1024 + scol;
  const f16* gA0 = pA0 + aoff;
  const f16* gB0 = pB0 + boff;
  const f16* gB1 = (NP >= 2) ? pB1 + boff : pB0 + boff;
  const f16* gA2 = (NP == 3) ? ep.A2 + aoff : pA0 + aoff;
  const f16* gB2 = (NP == 3) ? ep.B2 + boff : pB0 + boff;

  const int wr = w >> 1, wc = w & 1;
  const int fr = lane & 15;
  const int kb = (lane >> 4) * 8;
  const int ao = (wr * 64 + fr) * 32 + kb;
  const int bo = (wc * 64 + fr) * 32 + kb;

  auto stage = [&](int kt) {
    GLD(gA0 + kt, SA0 + w * 512); GLD(gA0 + kt + 65536, SA0 + 2048 + w * 512);
    GLD(gB0 + kt, SB0 + w * 512); GLD(gB0 + kt + 65536, SB0 + 2048 + w * 512);
    if constexpr (NP >= 2) {
      GLD(gB1 + kt, SB1 + w * 512); GLD(gB1 + kt + 65536, SB1 + 2048 + w * 512);
    }
    if constexpr (NP == 3) {
      GLD(gA2 + kt, SA2 + w * 512); GLD(gA2 + kt + 65536, SA2 + 2048 + w * 512);
      GLD(gB2 + kt, SB2 + w * 512); GLD(gB2 + kt + 65536, SB2 + 2048 + w * 512);
    }
  };

  f32x4 acc[4][4] = {};
  stage(0);

  for (int kt = 0; kt < 1024; kt += 32) {
    __syncthreads();  // staged GLDs complete
    f16x8 a0[4], b0[4], b1[4], a2[4], b2[4];
#pragma unroll
    for (int i = 0; i < 4; i++) a0[i] = *(const f16x8*)(SA0 + ao + i * 512);
#pragma unroll
    for (int i = 0; i < 4; i++) b0[i] = *(const f16x8*)(SB0 + bo + i * 512);
    if constexpr (NP >= 2) {
#pragma unroll
      for (int i = 0; i < 4; i++) b1[i] = *(const f16x8*)(SB1 + bo + i * 512);
    }
    if constexpr (NP == 3) {
#pragma unroll
      for (int i = 0; i < 4; i++) a2[i] = *(const f16x8*)(SA2 + ao + i * 512);
#pragma unroll
      for (int i = 0; i < 4; i++) b2[i] = *(const f16x8*)(SB2 + bo + i * 512);
    }
    __syncthreads();  // all waves done reading LDS
    if (kt < 992) stage(kt + 32);  // next-step loads fly under MFMA

    auto mm = [&](f16x8 (&fa)[4], f16x8 (&fb)[4]) {
#pragma unroll
      for (int mi = 0; mi < 4; mi++)
#pragma unroll
        for (int ni = 0; ni < 4; ni++)
          acc[mi][ni] = __builtin_amdgcn_mfma_f32_16x16x32_f16(fa[mi], fb[ni], acc[mi][ni], 0, 0, 0);
    };
    mm(a0, b0);
    if constexpr (NP >= 2) mm(a0, b1);
    if constexpr (NP == 3) mm(a2, b2);
  }

  if constexpr (NP == 1) {
    // scalar epilogue for weight-precompute modes (small grids)
    const int er = wr * 64 + ((lane >> 4) << 2);
    const int ec = wc * 64 + fr;
#pragma unroll
    for (int mi = 0; mi < 4; mi++)
#pragma unroll
      for (int ni = 0; ni < 4; ni++)
#pragma unroll
        for (int j = 0; j < 4; j++) {
          const int r = tmr + er + mi * 16 + j;
          const int c = tn + ec + ni * 16;
          const size_t i = (size_t)r * 1024 + c;
          const float av = acc[mi][ni][j];
          if constexpr (MODE == MG) {
            const float gv = av * (1.f / 1024.f);
            ep.of[zoO + i] = gv;
            ep.o0h[zoO + i] = (f16)gv;
          } else if constexpr (MODE == ME) {
            constexpr float C1 = 0.01f / 11.f;
            ep.o0h[zoO + i] = (f16)(32.f * (C1 * C1 * av - C1 * ep.rf0[zoO + i]));
          } else if constexpr (MODE == MWP) {
            const float* Wf = ly == 0 ? ep.w0 : ly == 1 ? ep.w1 : ly == 2 ? ep.w2 : ep.w3;
            const float s = 32.f * (Wf[(size_t)c * 1024 + r] + av * (1.f / 1024.f));
            const f16 hi = (f16)s;
            ep.o0h[zoO + i] = hi;
            ep.o0l[zoO + i] = (f16)(s - (float)hi);
          }
        }
  } else {
    // LDS-staged vectorized epilogue
    float* EPI = (float*)SMEM;
    const int ofs = (lane >> 4) << 2;
#pragma unroll
    for (int pp = 0; pp < 2; ++pp) {
      __syncthreads();  // staging LDS dead / prev pass reads done
#pragma unroll
      for (int mi2 = 0; mi2 < 2; ++mi2) {
#pragma unroll
        for (int ni = 0; ni < 4; ++ni)
#pragma unroll
          for (int j = 0; j < 4; ++j)
            EPI[(wr * 32 + mi2 * 16 + ofs + j) * 132 + wc * 64 + fr + ni * 16] =
                acc[pp * 2 + mi2][ni][j];
      }
      __syncthreads();
      const int rb = tid >> 2;
      const int co = (tid & 3) * 32;
      const int r = tmr + (rb >> 5) * 64 + pp * 32 + (rb & 31);
      const float* arow = EPI + rb * 132 + co;
#pragma unroll
      for (int chk = 0; chk < 4; ++chk) {
        const int c0 = tn + co + chk * 8;
        const size_t i = (size_t)r * 1024 + c0;
        float av[8];
        {
          const f32x4 q0 = *(const f32x4*)(arow + chk * 8);
          const f32x4 q1 = *(const f32x4*)(arow + chk * 8 + 4);
#pragma unroll
          for (int e = 0; e < 4; e++) { av[e] = q0[e]; av[4 + e] = q1[e]; }
        }
        if constexpr (MODE == MZ0) {
          float bia[8], bib[8], o0[8], o1[8], zz[8];
          ld_f8(ep.bias, c0, bia);
          ld_f8(ep.bias2, c0, bib);
#pragma unroll
          for (int e = 0; e < 8; e++) {
            const float z = av[e] * ep.sAi + bia[e];
            o0[e] = 0.1f * (z + 0.1f * bib[e]);
            o1[e] = 11.f * fmaxf(z, 0.f);
            zz[e] = 0.f;
          }
          st_pair8(ep.o0h, ep.o0l, i, o0, ep.sO);
          st_pair8(ep.o1h, ep.o1l, i, o1, ep.sO);
          st_pair8(ep.o2h, ep.o2l, i, zz, 1.f);
          st_f8(ep.of, i, zz);
        } else if constexpr (MODE == MVN) {
          float r2[8], v[8], s2n[8];
          ld_pair8(ep.x0h, ep.x0l, i, ep.sSi, r2);
#pragma unroll
          for (int e = 0; e < 8; e++) {
            v[e] = (r2[e] + av[e] * ep.sAi) * (1.f / 11.f);
            s2n[e] = 0.f;
          }
          if (ep.dos2) {
            float s2o[8], vo[8], qo[8];
            ld_pair8(ep.x2h, ep.x2l, i, ep.sPi, s2o);
            ld_s8(ep.x1s, i, ep.sPi, vo);
            ld_pair8(ep.x3h, ep.x3l, i, ep.sPi, qo);
#pragma unroll
            for (int e = 0; e < 8; e++)
              s2n[e] = -r2[e] - s2o[e] - vo[e] + 10.f * fmaxf(-qo[e], 0.f);
            st_pair8(ep.o1h, ep.o1l, i, s2n, ep.sO);
          }
          st_s8(ep.ov, i, v, ep.sO);  // after reading old v (x1s)
          float pv[8];
#pragma unroll
          for (int e = 0; e < 8; e++) pv[e] = v[e] + s2n[e];
          st_s8(ep.op, i, pv, ep.sO);
        } else if constexpr (MODE == MU || MODE == MUL) {
          float r1[8], s1v[8], q[8];
          ld_pair8(ep.x0h, ep.x0l, i, ep.sSi * 10.f, r1);
          ld_f8(ep.rf0, i, s1v);
#pragma unroll
          for (int e = 0; e < 8; e++) q[e] = r1[e] - 0.1f * (av[e] * ep.sAi) + s1v[e];
          if constexpr (MODE == MU) {
            st_pair8(ep.o0h, ep.o0l, i, q, ep.sO);
          } else {
#pragma unroll
            for (int e = 0; e < 8; e++) q[e] = -q[e];
            st_pair8(ep.o0h, ep.o0l, i, q, 1.f);
          }
        } else if constexpr (MODE == MQP) {
          if (!half2) {
            float qq[8], vv[8], s2[8], o[8];
            ld_pair8(ep.x0h, ep.x0l, i, ep.sSi, qq);
            ld_s8(ep.x1s, i, ep.sSi, vv);
            ld_pair8(ep.x2h, ep.x2l, i, ep.sSi, s2);
#pragma unroll
            for (int e = 0; e < 8; e++)
              o[e] = 10.f * vv[e] + 9.f * s2[e] + 10.f * fmaxf(-qq[e], 0.f)
                     - 0.1f * (av[e] * ep.sAi);
            st_pair8(ep.o0h, ep.o0l, i, o, ep.sO2);
          } else {
            float qq[8], s1v[8], bib[8], s1o[8], r1n[8];
            ld_pair8(ep.x0h, ep.x0l, i, ep.sSi, qq);
            ld_f8(ep.rf0, i, s1v);
            ld_f8(ep.bias2, c0, bib);
#pragma unroll
            for (int e = 0; e < 8; e++) {
              const float pW = av[e] * ep.sAi;
              s1o[e] = -(qq[e] - s1v[e]) - 0.1f * pW;
              r1n[e] = 0.1f * (0.1f * bib[e] - s1v[e] + 0.1f * pW);
            }
            st_f8(ep.of, i, s1o);
            st_pair8(ep.o1h, ep.o1l, i, r1n, ep.sO2);
          }
        }
      }
    }
  }
}

template <int MC>
__global__ void mcprobe() {}  // Mc diagnostic

// x: pad 784->1024, x16, hi plane only
__global__ __launch_bounds__(256) void xstage(const float* __restrict__ src,
                                              f16* __restrict__ h) {
  const size_t i = (size_t)blockIdx.x * 256 + threadIdx.x;
  const int k = (int)(i & 1023);
  const size_t m = i >> 10;
  h[i] = (f16)((k < 784) ? 16.f * src[m * 784 + k] : 0.f);
}

// Win: pad 784->1024, x32 split
__global__ __launch_bounds__(256) void winstage(const float* __restrict__ src,
                                                f16* __restrict__ h, f16* __restrict__ l) {
  const size_t i = (size_t)blockIdx.x * 256 + threadIdx.x;
  const int k = (int)(i & 1023);
  const size_t m = i >> 10;
  const float s = (k < 784) ? 32.f * src[m * 784 + k] : 0.f;
  const f16 hi = (f16)s;
  h[i] = hi;
  l[i] = (f16)(s - (float)hi);
}

// 4 layer weights -> x32 split, direct + transposed
__global__ __launch_bounds__(256) void wstage(const float* __restrict__ W0, const float* __restrict__ W1,
                                              const float* __restrict__ W2, const float* __restrict__ W3,
                                              f16* __restrict__ Wh, f16* __restrict__ Wl,
                                              f16* __restrict__ WTh, f16* __restrict__ WTl) {
  __shared__ float t[32][33];
  const int lz = blockIdx.z;
  const float* W = lz == 0 ? W0 : lz == 1 ? W1 : lz == 2 ? W2 : W3;
  const size_t off = (size_t)lz * 1024 * 1024;
  const int c0 = blockIdx.x * 32, r0 = blockIdx.y * 32;
  const int tx = threadIdx.x, ty = threadIdx.y;
#pragma unroll
  for (int i = ty; i < 32; i += 8) {
    const float v = W[(size_t)(r0 + i) * 1024 + c0 + tx];
    t[i][tx] = v;
    const float s = 32.f * v;
    const f16 hi = (f16)s;
    Wh[off + (size_t)(r0 + i) * 1024 + c0 + tx] = hi;
    Wl[off + (size_t)(r0 + i) * 1024 + c0 + tx] = (f16)(s - (float)hi);
  }
  __syncthreads();
#pragma unroll
  for (int i = ty; i < 32; i += 8) {
    const float s = 32.f * t[tx][i];
    const f16 hi = (f16)s;
    WTh[off + (size_t)(c0 + i) * 1024 + r0 + tx] = hi;
    WTl[off + (size_t)(c0 + i) * 1024 + r0 + tx] = (f16)(s - (float)hi);
  }
}

// logits = softmax(rec(L) @ Wout^T + bout); one wave per row
__global__ __launch_bounds__(256) void out_softmax(const f16* __restrict__ Lh, const f16* __restrict__ Ll,
                                                   const float* __restrict__ Wout,
                                                   const float* __restrict__ bo,
                                                   float* __restrict__ out) {
  const int row = blockIdx.x * 4 + (threadIdx.x >> 6);
  const int lane = threadIdx.x & 63;
  const size_t rb = (size_t)row * 1024;
  float p[10];
#pragma unroll
  for (int t = 0; t < 10; t++) p[t] = 0.f;
#pragma unroll
  for (int j = 0; j < 4; j++) {
    const int kbase = (j * 64 + lane) * 4;
    const f16x4 hv = *(const f16x4*)(Lh + rb + kbase);
    const f16x4 lv = *(const f16x4*)(Ll + rb + kbase);
    float uv[4];
#pragma unroll
    for (int e = 0; e < 4; e++) uv[e] = (float)hv[e] + (float)lv[e];
#pragma unroll
    for (int t = 0; t < 10; t++) {
      const float4 wv = *(const float4*)(Wout + t * 1024 + kbase);
      p[t] += uv[0] * wv.x + uv[1] * wv.y + uv[2] * wv.z + uv[3] * wv.w;
    }
  }
#pragma unroll
  for (int off = 32; off; off >>= 1)
#pragma unroll
    for (int t = 0; t < 10; t++) p[t] += __shfl_down(p[t], off);
  if (lane == 0) {
    float lg[10], m = -1e30f, s = 0.f;
#pragma unroll
    for (int t = 0; t < 10; t++) { lg[t] = p[t] + bo[t]; m = fmaxf(m, lg[t]); }
#pragma unroll
    for (int t = 0; t < 10; t++) { lg[t] = expf(lg[t] - m); s += lg[t]; }
    const float inv = 1.f / s;
    float* o = out + (size_t)row * 10;
#pragma unroll
    for (int t = 0; t < 10; t++) o[t] = lg[t] * inv;
  }
}

extern "C" void kernel_launch(void* const* d_in, const int* in_sizes, int n_in,
                              void* d_out, int out_size, void* d_ws, size_t ws_size,
                              hipStream_t stream) {
  const float* x = (const float*)d_in[0];
  const float* Win = (const float*)d_in[1];
  const float* bin = (const float*)d_in[2];
  const float* Wgt[4] = {(const float*)d_in[3], (const float*)d_in[5],
                         (const float*)d_in[7], (const float*)d_in[9]};
  const float* bl[4] = {(const float*)d_in[4], (const float*)d_in[6],
                        (const float*)d_in[8], (const float*)d_in[10]};
  const float* Wout = (const float*)d_in[11];
  const float* bout = (const float*)d_in[12];
  float* out = (float*)d_out;

  char* p = (char*)d_ws;
  auto take = [&](size_t n) {
    void* q = (void*)p;
    p += (n + 255) & ~(size_t)255;
    return q;
  };
  const size_t UM = (size_t)1024 * 1024;

  // weights (~60MB)
  f16* Winh = (f16*)take(UM * 2);
  f16* Winl = (f16*)take(UM * 2);
  f16* Wh = (f16*)take(4 * UM * 2);
  f16* Wl = (f16*)take(4 * UM * 2);
  f16* WTh = (f16*)take(4 * UM * 2);
  f16* WTl = (f16*)take(4 * UM * 2);
  f16* WpTh = (f16*)take(4 * UM * 2);
  f16* WpTl = (f16*)take(4 * UM * 2);
  f16* E32 = (f16*)take(4 * UM * 2);
  const size_t fixedB = (size_t)(p - (char*)d_ws);

  int Mc = 8192;
  auto actB = [&](int m) {
    size_t a = (size_t)m * 1024 * 24;  // 10 f16 planes + 1 f32
    if (m < 4096) a += 24 * UM;        // dedicated G scratch
    return a;
  };
  while (Mc > 1024 && fixedB + actB(Mc) + 65536 > ws_size) Mc >>= 1;
  if (fixedB + actB(Mc) + 65536 > ws_size) return;
  const size_t CF = (size_t)Mc * 1024;

  f16* P0h = (f16*)take(CF * 2); f16* P0l = (f16*)take(CF * 2);
  f16* Qh = (f16*)take(CF * 2);  f16* Ql = (f16*)take(CF * 2);
  f16* R2h = (f16*)take(CF * 2); f16* R2l = (f16*)take(CF * 2);
  f16* S2h = (f16*)take(CF * 2); f16* S2l = (f16*)take(CF * 2);
  f16* Vh = (f16*)take(CF * 2);
  f16* Ph = (f16*)take(CF * 2);
  float* S1 = (float*)take(CF * 4);
  float* Gf;
  f16* Gh;
  if (Mc >= 4096) {    // alias precompute scratch over act planes (dead then)
    Gf = (float*)P0h;  // 16MB over P0h+P0l
    Gh = (f16*)Qh;     // 8MB over Qh
  } else {
    Gf = (float*)take(4 * UM * 4);
    Gh = (f16*)take(4 * UM * 2);
  }

  switch (Mc) {
    case 8192: mcprobe<8><<<1, 1, 0, stream>>>(); break;
    case 4096: mcprobe<4><<<1, 1, 0, stream>>>(); break;
    case 2048: mcprobe<2><<<1, 1, 0, stream>>>(); break;
    default:   mcprobe<1><<<1, 1, 0, stream>>>(); break;
  }

  // ---- weight precompute (batched over 4 layers via blockIdx.y) ----
  winstage<<<dim3((unsigned)(UM / 256)), 256, 0, stream>>>(Win, Winh, Winl);
  wstage<<<dim3(32, 32, 4), dim3(32, 8), 0, stream>>>(Wgt[0], Wgt[1], Wgt[2], Wgt[3],
                                                      Wh, Wl, WTh, WTl);
  {  // G = W^T W (hi-only)
    Ep e{};
    e.Ah = WTh; e.Bh = WTh;
    e.zA = UM; e.zB = UM; e.zO = UM;
    e.of = Gf; e.o0h = Gh;
    gk<MG><<<dim3(64, 4), 256, 0, stream>>>(e);
  }
  {  // E32 = 32*(c^2 G^2 - c G)
    Ep e{};
    e.Ah = Gh; e.Bh = Gh; e.zA = UM; e.zB = UM; e.zO = UM;
    e.rf0 = Gf; e.o0h = E32;
    gk<ME><<<dim3(64, 4), 256, 0, stream>>>(e);
  }
  {  // WpT = W^T + E @ W^T (x32 split)
    Ep e{};
    e.Ah = E32; e.Bh = Wh; e.zA = UM; e.zB = UM; e.zO = UM;
    e.w0 = Wgt[0]; e.w1 = Wgt[1]; e.w2 = Wgt[2]; e.w3 = Wgt[3];
    e.o0h = WpTh; e.o0l = WpTl;
    gk<MWP><<<dim3(64, 4), 256, 0, stream>>>(e);
  }

  const float SIG[5] = {16.f, 2.f, 0.25f, 0.03125f, 1.f};
  const int nch = 8192 / Mc;
  const dim3 gg((unsigned)(Mc / 128) * 8);
  const dim3 gg2((unsigned)(Mc / 128) * 16);

  for (int ch = 0; ch < nch; ++ch) {
    const size_t r0 = (size_t)ch * Mc;
    xstage<<<dim3(Mc * 4), 256, 0, stream>>>(x + r0 * 784, Qh);
    {  // Z0: z = x@Win^T + b_in -> P0 (0.1*r1), R2, S2=0, S1=0
      Ep e{};
      e.Ah = Qh; e.Bh = Winh; e.Bl = Winl;
      e.bias = bin; e.bias2 = bl[0];
      e.o0h = P0h; e.o0l = P0l; e.o1h = R2h; e.o1l = R2l; e.o2h = S2h; e.o2l = S2l;
      e.of = S1; e.sAi = 1.f / 512.f; e.sO = 16.f;
      e.Mh = 1 << 30;
      gk<MZ0><<<gg, 256, 0, stream>>>(e);
    }
    for (int l = 0; l < 4; l++) {
      const size_t lz = (size_t)l * UM;
      const float sl = SIG[l];
      f16 *bCh = (l & 1) ? Qh : P0h, *bCl = (l & 1) ? Ql : P0l;  // r1_l -> q_l
      f16 *bAh = (l & 1) ? P0h : Qh, *bAl = (l & 1) ? P0l : Ql;  // q_{l-1} / r1_{l+1}
      {  // VNEW: v = (r2 + 0.1 r1@Wp + r2@E)/11 -> Vh ; s2(l) -> S2 ; p -> Ph
        Ep e{};
        e.Ah = bCh; e.Bh = WpTh + lz; e.Bl = WpTl + lz;
        e.A2 = R2h; e.B2 = E32 + lz;
        e.x0h = R2h; e.x0l = R2l;
        e.x1s = Vh;
        e.x2h = S2h; e.x2l = S2l;
        e.x3h = bAh; e.x3l = bAl;
        e.ov = Vh; e.op = Ph; e.o1h = S2h; e.o1l = S2l;
        e.sAi = 1.f / (32.f * sl); e.sSi = 1.f / sl;
        e.sPi = l ? 1.f / SIG[l - 1] : 0.f; e.sO = sl;
        e.dos2 = l ? 1 : 0; e.Mh = 1 << 30;
        gk<MVN><<<gg, 256, 0, stream>>>(e);
      }
      if (l < 3) {
        {  // U: q = 10*(0.1 r1) - 0.1 v@W^T + s1 -> in-place over r1
          Ep e{};
          e.Ah = Vh; e.Bh = Wh + lz; e.Bl = Wl + lz;
          e.x0h = bCh; e.x0l = bCl; e.rf0 = S1;
          e.o0h = bCh; e.o0l = bCl;
          e.sAi = 1.f / (32.f * sl); e.sSi = 1.f / sl; e.sO = sl;
          e.Mh = 1 << 30;
          gk<MU><<<gg, 256, 0, stream>>>(e);
        }
        {  // QP: q-half q@W -> r2' ; p-half p@W^T -> s1', r1'
          Ep e{};
          e.Ah = bCh; e.Bh = WTh + lz; e.Bl = WTl + lz;
          e.Ch = Ph; e.Dh = Wh + lz; e.Dl = Wl + lz;
          e.x0h = bCh; e.x0l = bCl;
          e.x1s = Vh;
          e.x2h = S2h; e.x2l = S2l;
          e.rf0 = S1; e.of = S1;
          e.o0h = R2h; e.o0l = R2l;    // r2'
          e.o1h = bAh; e.o1l = bAl;    // 0.1*r1'
          e.bias2 = bl[l + 1];
          e.sAi = 1.f / (32.f * sl); e.sSi = 1.f / sl; e.sO2 = SIG[l + 1];
          e.Mh = Mc;
          gk<MQP><<<gg2, 256, 0, stream>>>(e);
        }
      } else {  // UL: logits = -(10*(0.1 r1) - 0.1 v@W^T + s1) -> R2 pair (scale 1)
        Ep e{};
        e.Ah = Vh; e.Bh = Wh + lz; e.Bl = Wl + lz;
        e.x0h = bCh; e.x0l = bCl; e.rf0 = S1;
        e.o0h = R2h; e.o0l = R2l;
        e.sAi = 1.f / (32.f * sl); e.sSi = 1.f / sl; e.sO = 1.f;
        e.Mh = 1 << 30;
        gk<MUL><<<gg, 256, 0, stream>>>(e);
      }
    }
    out_softmax<<<dim3(Mc / 4), 256, 0, stream>>>(R2h, R2l, Wout, bout, out + r0 * 10);
  }
}

// Round 13
// 1545.167 us; speedup vs baseline: 1.0854x; 1.0854x over previous
//
#include <hip/hip_runtime.h>

typedef _Float16 f16;
typedef _Float16 f16x8 __attribute__((ext_vector_type(8)));
typedef _Float16 f16x4 __attribute__((ext_vector_type(4)));
typedef float f32x4 __attribute__((ext_vector_type(4)));

#define GLD(g, l) __builtin_amdgcn_global_load_lds( \
    (const __attribute__((address_space(1))) void*)(g), \
    (__attribute__((address_space(3))) void*)(l), 16, 0, 0)

enum { MZ0, MVN, MU, MUL, MQP, MG, ME, MWP };

struct Ep {
  const f16 *Ah, *Bh, *Bl;       // primary: A (1 plane) x B (2 planes)
  const f16 *A2, *B2;            // VNEW extra pass: r2h @ E32
  const f16 *Ch, *Dh, *Dl;       // QP p-half: ph @ {Wh, Wl}
  f16 *o0h, *o0l, *o1h, *o1l, *o2h, *o2l;
  f16 *ov, *op;                  // single-plane outs (v, p)
  float* of;
  const f16 *x0h, *x0l, *x2h, *x2l, *x3h, *x3l;
  const f16* x1s;                // single-plane read (v)
  const float* rf0;
  const float *w0, *w1, *w2, *w3;
  const float *bias, *bias2;
  float sAi, sSi, sPi, sO, sO2;
  int Mh, dos2;
  size_t zA, zB, zO;
};

__device__ __forceinline__ float rec2(const f16* h, const f16* l, size_t i) {
  return (float)h[i] + (float)l[i];
}
__device__ __forceinline__ void wp2(f16* h, f16* l, size_t i, float v) {
  const f16 hi = (f16)v;
  h[i] = hi;
  l[i] = (f16)(v - (float)hi);
}

// C = sum_passes A_p @ B_p^T; 64x128 tiles, BK=32, 4 waves (2x2: 2 m-frags x 4 n-frags).
// NP=1 {A@B0}; NP=2 {A@B0, A@B1}; NP=3 (VNEW) {.., A2@B2}. A single-plane, B split.
// Rotated K-loop (stage next step under MFMA) + chunked XCD swizzle (XCD owns tm band).
// 64-row tiles double the grid vs 128^2 -> 4+ blocks/CU (the r11 2-blocks/CU ceiling).
template <int MODE>
__global__ __launch_bounds__(256, 4) void gk(Ep ep) {
  constexpr int NP = (MODE == MVN) ? 3
                   : (MODE == MG || MODE == ME || MODE == MWP) ? 1 : 2;
  __shared__ f16 SA0[2048] __attribute__((aligned(16)));
  __shared__ f16 SB0[4096] __attribute__((aligned(16)));
  __shared__ f16 SB1[NP >= 2 ? 4096 : 16] __attribute__((aligned(16)));
  __shared__ f16 SA2[NP == 3 ? 2048 : 16] __attribute__((aligned(16)));
  __shared__ f16 SB2[NP == 3 ? 4096 : 16] __attribute__((aligned(16)));
  const int tid = threadIdx.x;
  const int w = tid >> 6, lane = tid & 63;
  const unsigned nb = gridDim.x;
  const unsigned bid = blockIdx.x;
  const unsigned swz = (bid & 7) * (nb >> 3) + (bid >> 3);  // bijective, nb%8==0
  const int tn = (int)(swz & 7) * 128;
  const int tm = (int)(swz >> 3) * 64;
  const int ly = blockIdx.y;
  const size_t zoA = (size_t)ly * ep.zA;
  const size_t zoB = (size_t)ly * ep.zB;
  const size_t zoO = (size_t)ly * ep.zO;

  const bool half2 = (MODE == MQP) && (tm >= ep.Mh);
  const int tmr = half2 ? tm - ep.Mh : tm;

  const f16* pA0 = half2 ? ep.Ch : ep.Ah;
  const f16* pB0 = half2 ? ep.Dh : ep.Bh;
  const f16* pB1 = half2 ? ep.Dl : ep.Bl;

  const int srow = w * 16 + (lane >> 2);  // 0..63
  const int scol = (lane & 3) * 8;
  const size_t aoff = zoA + (size_t)(tmr + srow) * 1024 + scol;
  const size_t boff = zoB + (size_t)(tn + srow) * 1024 + scol;
  const f16* gA0 = pA0 + aoff;
  const f16* gB0 = pB0 + boff;
  const f16* gB1 = (NP >= 2) ? pB1 + boff : pB0 + boff;
  const f16* gA2 = (NP == 3) ? ep.A2 + aoff : pA0 + aoff;
  const f16* gB2 = (NP == 3) ? ep.B2 + boff : pB0 + boff;

  const int wr = w >> 1, wc = w & 1;
  const int fr = lane & 15;
  const int kb = (lane >> 4) * 8;
  const int ao = (wr * 32 + fr) * 32 + kb;
  const int bo = (wc * 64 + fr) * 32 + kb;

  auto stage = [&](int kt) {
    GLD(gA0 + kt, SA0 + w * 512);
    GLD(gB0 + kt, SB0 + w * 512); GLD(gB0 + kt + 65536, SB0 + 2048 + w * 512);
    if constexpr (NP >= 2) {
      GLD(gB1 + kt, SB1 + w * 512); GLD(gB1 + kt + 65536, SB1 + 2048 + w * 512);
    }
    if constexpr (NP == 3) {
      GLD(gA2 + kt, SA2 + w * 512);
      GLD(gB2 + kt, SB2 + w * 512); GLD(gB2 + kt + 65536, SB2 + 2048 + w * 512);
    }
  };

  f32x4 acc[2][4] = {};
  stage(0);

  for (int kt = 0; kt < 1024; kt += 32) {
    __syncthreads();  // staged GLDs complete
    f16x8 a0[2], b0[4], b1[4], a2[2], b2[4];
#pragma unroll
    for (int i = 0; i < 2; i++) a0[i] = *(const f16x8*)(SA0 + ao + i * 512);
#pragma unroll
    for (int i = 0; i < 4; i++) b0[i] = *(const f16x8*)(SB0 + bo + i * 512);
    if constexpr (NP >= 2) {
#pragma unroll
      for (int i = 0; i < 4; i++) b1[i] = *(const f16x8*)(SB1 + bo + i * 512);
    }
    if constexpr (NP == 3) {
#pragma unroll
      for (int i = 0; i < 2; i++) a2[i] = *(const f16x8*)(SA2 + ao + i * 512);
#pragma unroll
      for (int i = 0; i < 4; i++) b2[i] = *(const f16x8*)(SB2 + bo + i * 512);
    }
    __syncthreads();  // all waves done reading LDS
    if (kt < 992) stage(kt + 32);  // next-step loads fly under MFMA

    auto mm = [&](f16x8 (&fa)[2], f16x8 (&fb)[4]) {
#pragma unroll
      for (int mi = 0; mi < 2; mi++)
#pragma unroll
        for (int ni = 0; ni < 4; ni++)
          acc[mi][ni] = __builtin_amdgcn_mfma_f32_16x16x32_f16(fa[mi], fb[ni], acc[mi][ni], 0, 0, 0);
    };
    mm(a0, b0);
    if constexpr (NP >= 2) mm(a0, b1);
    if constexpr (NP == 3) mm(a2, b2);
  }

  // C/D layout: col = lane&15, row = (lane>>4)*4 + j
  const int er = wr * 32 + ((lane >> 4) << 2);
  const int ec = wc * 64 + fr;
#pragma unroll
  for (int mi = 0; mi < 2; mi++)
#pragma unroll
    for (int ni = 0; ni < 4; ni++)
#pragma unroll
      for (int j = 0; j < 4; j++) {
        const int r = tmr + er + mi * 16 + j;
        const int c = tn + ec + ni * 16;
        const size_t i = (size_t)r * 1024 + c;
        const float av = acc[mi][ni][j];
        if constexpr (MODE == MZ0) {
          const float z = av * ep.sAi + ep.bias[c];
          wp2(ep.o0h, ep.o0l, i, 0.1f * (z + 0.1f * ep.bias2[c]) * ep.sO);  // 0.1*r1*SIG
          wp2(ep.o1h, ep.o1l, i, 11.f * fmaxf(z, 0.f) * ep.sO);            // r2*SIG
          wp2(ep.o2h, ep.o2l, i, 0.f);                                     // s2 = 0
          ep.of[i] = 0.f;                                                  // s1 = 0
        } else if constexpr (MODE == MVN) {
          const float G = av * ep.sAi;                  // 0.1*r1@Wp + r2@E
          const float r2 = rec2(ep.x0h, ep.x0l, i) * ep.sSi;
          const float v = (r2 + G) * (1.f / 11.f);
          float s2n = 0.f;
          if (ep.dos2) {
            const float s2o = rec2(ep.x2h, ep.x2l, i) * ep.sPi;
            const float vo = (float)ep.x1s[i] * ep.sPi;
            const float qo = rec2(ep.x3h, ep.x3l, i) * ep.sPi;
            s2n = -r2 - s2o - vo + 10.f * fmaxf(-qo, 0.f);
            wp2(ep.o1h, ep.o1l, i, s2n * ep.sO);        // s2(l)
          }
          ep.ov[i] = (f16)(v * ep.sO);                  // v (after reading old v)
          ep.op[i] = (f16)((v + s2n) * ep.sO);          // p = v + s2
        } else if constexpr (MODE == MU || MODE == MUL) {
          const float vW = av * ep.sAi;
          const float r1 = rec2(ep.x0h, ep.x0l, i) * ep.sSi * 10.f;
          const float q = r1 - 0.1f * vW + ep.rf0[i];
          if constexpr (MODE == MU)
            wp2(ep.o0h, ep.o0l, i, q * ep.sO);          // q in-place over r1
          else
            wp2(ep.o0h, ep.o0l, i, -q);                 // logits (scale 1)
        } else if constexpr (MODE == MQP) {
          if (!half2) {
            const float qW = av * ep.sAi;
            const float v = (float)ep.x1s[i] * ep.sSi;
            const float s2 = rec2(ep.x2h, ep.x2l, i) * ep.sSi;
            const float qq = rec2(ep.x0h, ep.x0l, i) * ep.sSi;
            wp2(ep.o0h, ep.o0l, i,
                (10.f * v + 9.f * s2 + 10.f * fmaxf(-qq, 0.f) - 0.1f * qW) * ep.sO2);  // r2'
          } else {
            const float pW = av * ep.sAi;
            const float s1 = ep.rf0[i];
            const float qq = rec2(ep.x0h, ep.x0l, i) * ep.sSi;
            ep.of[i] = -(qq - s1) - 0.1f * pW;                                          // s1'
            wp2(ep.o1h, ep.o1l, i, 0.1f * (0.1f * ep.bias2[c] - s1 + 0.1f * pW) * ep.sO2);  // 0.1*r1'
          }
        } else if constexpr (MODE == MG) {
          const float gv = av * (1.f / 1024.f);
          ep.of[zoO + i] = gv;
          ep.o0h[zoO + i] = (f16)gv;
        } else if constexpr (MODE == ME) {
          constexpr float C1 = 0.01f / 11.f;
          ep.o0h[zoO + i] = (f16)(32.f * (C1 * C1 * av - C1 * ep.rf0[zoO + i]));
        } else if constexpr (MODE == MWP) {
          const float* Wf = ly == 0 ? ep.w0 : ly == 1 ? ep.w1 : ly == 2 ? ep.w2 : ep.w3;
          const float s = 32.f * (Wf[(size_t)c * 1024 + r] + av * (1.f / 1024.f));  // WpT
          const f16 hi = (f16)s;
          ep.o0h[zoO + i] = hi;
          ep.o0l[zoO + i] = (f16)(s - (float)hi);
        }
      }
}

template <int MC>
__global__ void mcprobe() {}  // Mc diagnostic

// x: pad 784->1024, x16, hi plane only
__global__ __launch_bounds__(256) void xstage(const float* __restrict__ src,
                                              f16* __restrict__ h) {
  const size_t i = (size_t)blockIdx.x * 256 + threadIdx.x;
  const int k = (int)(i & 1023);
  const size_t m = i >> 10;
  h[i] = (f16)((k < 784) ? 16.f * src[m * 784 + k] : 0.f);
}

// Win: pad 784->1024, x32 split
__global__ __launch_bounds__(256) void winstage(const float* __restrict__ src,
                                                f16* __restrict__ h, f16* __restrict__ l) {
  const size_t i = (size_t)blockIdx.x * 256 + threadIdx.x;
  const int k = (int)(i & 1023);
  const size_t m = i >> 10;
  const float s = (k < 784) ? 32.f * src[m * 784 + k] : 0.f;
  const f16 hi = (f16)s;
  h[i] = hi;
  l[i] = (f16)(s - (float)hi);
}

// 4 layer weights -> x32 split, direct + transposed
__global__ __launch_bounds__(256) void wstage(const float* __restrict__ W0, const float* __restrict__ W1,
                                              const float* __restrict__ W2, const float* __restrict__ W3,
                                              f16* __restrict__ Wh, f16* __restrict__ Wl,
                                              f16* __restrict__ WTh, f16* __restrict__ WTl) {
  __shared__ float t[32][33];
  const int lz = blockIdx.z;
  const float* W = lz == 0 ? W0 : lz == 1 ? W1 : lz == 2 ? W2 : W3;
  const size_t off = (size_t)lz * 1024 * 1024;
  const int c0 = blockIdx.x * 32, r0 = blockIdx.y * 32;
  const int tx = threadIdx.x, ty = threadIdx.y;
#pragma unroll
  for (int i = ty; i < 32; i += 8) {
    const float v = W[(size_t)(r0 + i) * 1024 + c0 + tx];
    t[i][tx] = v;
    const float s = 32.f * v;
    const f16 hi = (f16)s;
    Wh[off + (size_t)(r0 + i) * 1024 + c0 + tx] = hi;
    Wl[off + (size_t)(r0 + i) * 1024 + c0 + tx] = (f16)(s - (float)hi);
  }
  __syncthreads();
#pragma unroll
  for (int i = ty; i < 32; i += 8) {
    const float s = 32.f * t[tx][i];
    const f16 hi = (f16)s;
    WTh[off + (size_t)(c0 + i) * 1024 + r0 + tx] = hi;
    WTl[off + (size_t)(c0 + i) * 1024 + r0 + tx] = (f16)(s - (float)hi);
  }
}

// logits = softmax(rec(L) @ Wout^T + bout); one wave per row
__global__ __launch_bounds__(256) void out_softmax(const f16* __restrict__ Lh, const f16* __restrict__ Ll,
                                                   const float* __restrict__ Wout,
                                                   const float* __restrict__ bo,
                                                   float* __restrict__ out) {
  const int row = blockIdx.x * 4 + (threadIdx.x >> 6);
  const int lane = threadIdx.x & 63;
  const size_t rb = (size_t)row * 1024;
  float p[10];
#pragma unroll
  for (int t = 0; t < 10; t++) p[t] = 0.f;
#pragma unroll
  for (int j = 0; j < 4; j++) {
    const int kbase = (j * 64 + lane) * 4;
    const f16x4 hv = *(const f16x4*)(Lh + rb + kbase);
    const f16x4 lv = *(const f16x4*)(Ll + rb + kbase);
    float uv[4];
#pragma unroll
    for (int e = 0; e < 4; e++) uv[e] = (float)hv[e] + (float)lv[e];
#pragma unroll
    for (int t = 0; t < 10; t++) {
      const float4 wv = *(const float4*)(Wout + t * 1024 + kbase);
      p[t] += uv[0] * wv.x + uv[1] * wv.y + uv[2] * wv.z + uv[3] * wv.w;
    }
  }
#pragma unroll
  for (int off = 32; off; off >>= 1)
#pragma unroll
    for (int t = 0; t < 10; t++) p[t] += __shfl_down(p[t], off);
  if (lane == 0) {
    float lg[10], m = -1e30f, s = 0.f;
#pragma unroll
    for (int t = 0; t < 10; t++) { lg[t] = p[t] + bo[t]; m = fmaxf(m, lg[t]); }
#pragma unroll
    for (int t = 0; t < 10; t++) { lg[t] = expf(lg[t] - m); s += lg[t]; }
    const float inv = 1.f / s;
    float* o = out + (size_t)row * 10;
#pragma unroll
    for (int t = 0; t < 10; t++) o[t] = lg[t] * inv;
  }
}

extern "C" void kernel_launch(void* const* d_in, const int* in_sizes, int n_in,
                              void* d_out, int out_size, void* d_ws, size_t ws_size,
                              hipStream_t stream) {
  const float* x = (const float*)d_in[0];
  const float* Win = (const float*)d_in[1];
  const float* bin = (const float*)d_in[2];
  const float* Wgt[4] = {(const float*)d_in[3], (const float*)d_in[5],
                         (const float*)d_in[7], (const float*)d_in[9]};
  const float* bl[4] = {(const float*)d_in[4], (const float*)d_in[6],
                        (const float*)d_in[8], (const float*)d_in[10]};
  const float* Wout = (const float*)d_in[11];
  const float* bout = (const float*)d_in[12];
  float* out = (float*)d_out;

  char* p = (char*)d_ws;
  auto take = [&](size_t n) {
    void* q = (void*)p;
    p += (n + 255) & ~(size_t)255;
    return q;
  };
  const size_t UM = (size_t)1024 * 1024;

  // weights (~60MB)
  f16* Winh = (f16*)take(UM * 2);
  f16* Winl = (f16*)take(UM * 2);
  f16* Wh = (f16*)take(4 * UM * 2);
  f16* Wl = (f16*)take(4 * UM * 2);
  f16* WTh = (f16*)take(4 * UM * 2);
  f16* WTl = (f16*)take(4 * UM * 2);
  f16* WpTh = (f16*)take(4 * UM * 2);
  f16* WpTl = (f16*)take(4 * UM * 2);
  f16* E32 = (f16*)take(4 * UM * 2);
  const size_t fixedB = (size_t)(p - (char*)d_ws);

  int Mc = 8192;
  auto actB = [&](int m) {
    size_t a = (size_t)m * 1024 * 24;  // 10 f16 planes + 1 f32
    if (m < 4096) a += 24 * UM;        // dedicated G scratch
    return a;
  };
  while (Mc > 1024 && fixedB + actB(Mc) + 65536 > ws_size) Mc >>= 1;
  if (fixedB + actB(Mc) + 65536 > ws_size) return;
  const size_t CF = (size_t)Mc * 1024;

  f16* P0h = (f16*)take(CF * 2); f16* P0l = (f16*)take(CF * 2);
  f16* Qh = (f16*)take(CF * 2);  f16* Ql = (f16*)take(CF * 2);
  f16* R2h = (f16*)take(CF * 2); f16* R2l = (f16*)take(CF * 2);
  f16* S2h = (f16*)take(CF * 2); f16* S2l = (f16*)take(CF * 2);
  f16* Vh = (f16*)take(CF * 2);
  f16* Ph = (f16*)take(CF * 2);
  float* S1 = (float*)take(CF * 4);
  float* Gf;
  f16* Gh;
  if (Mc >= 4096) {    // alias precompute scratch over act planes (dead then)
    Gf = (float*)P0h;  // 16MB over P0h+P0l
    Gh = (f16*)Qh;     // 8MB over Qh
  } else {
    Gf = (float*)take(4 * UM * 4);
    Gh = (f16*)take(4 * UM * 2);
  }

  switch (Mc) {
    case 8192: mcprobe<8><<<1, 1, 0, stream>>>(); break;
    case 4096: mcprobe<4><<<1, 1, 0, stream>>>(); break;
    case 2048: mcprobe<2><<<1, 1, 0, stream>>>(); break;
    default:   mcprobe<1><<<1, 1, 0, stream>>>(); break;
  }

  // ---- weight precompute (batched over 4 layers via blockIdx.y) ----
  winstage<<<dim3((unsigned)(UM / 256)), 256, 0, stream>>>(Win, Winh, Winl);
  wstage<<<dim3(32, 32, 4), dim3(32, 8), 0, stream>>>(Wgt[0], Wgt[1], Wgt[2], Wgt[3],
                                                      Wh, Wl, WTh, WTl);
  {  // G = W^T W (hi-only)
    Ep e{};
    e.Ah = WTh; e.Bh = WTh;
    e.zA = UM; e.zB = UM; e.zO = UM;
    e.of = Gf; e.o0h = Gh;
    gk<MG><<<dim3(128, 4), 256, 0, stream>>>(e);
  }
  {  // E32 = 32*(c^2 G^2 - c G)
    Ep e{};
    e.Ah = Gh; e.Bh = Gh; e.zA = UM; e.zB = UM; e.zO = UM;
    e.rf0 = Gf; e.o0h = E32;
    gk<ME><<<dim3(128, 4), 256, 0, stream>>>(e);
  }
  {  // WpT = W^T + E @ W^T (x32 split)
    Ep e{};
    e.Ah = E32; e.Bh = Wh; e.zA = UM; e.zB = UM; e.zO = UM;
    e.w0 = Wgt[0]; e.w1 = Wgt[1]; e.w2 = Wgt[2]; e.w3 = Wgt[3];
    e.o0h = WpTh; e.o0l = WpTl;
    gk<MWP><<<dim3(128, 4), 256, 0, stream>>>(e);
  }

  const float SIG[5] = {16.f, 2.f, 0.25f, 0.03125f, 1.f};
  const int nch = 8192 / Mc;
  const dim3 gg((unsigned)(Mc / 64) * 8);
  const dim3 gg2((unsigned)(Mc / 64) * 16);

  for (int ch = 0; ch < nch; ++ch) {
    const size_t r0 = (size_t)ch * Mc;
    xstage<<<dim3(Mc * 4), 256, 0, stream>>>(x + r0 * 784, Qh);
    {  // Z0: z = x@Win^T + b_in -> P0 (0.1*r1), R2, S2=0, S1=0
      Ep e{};
      e.Ah = Qh; e.Bh = Winh; e.Bl = Winl;
      e.bias = bin; e.bias2 = bl[0];
      e.o0h = P0h; e.o0l = P0l; e.o1h = R2h; e.o1l = R2l; e.o2h = S2h; e.o2l = S2l;
      e.of = S1; e.sAi = 1.f / 512.f; e.sO = 16.f;
      e.Mh = 1 << 30;
      gk<MZ0><<<gg, 256, 0, stream>>>(e);
    }
    for (int l = 0; l < 4; l++) {
      const size_t lz = (size_t)l * UM;
      const float sl = SIG[l];
      f16 *bCh = (l & 1) ? Qh : P0h, *bCl = (l & 1) ? Ql : P0l;  // r1_l -> q_l
      f16 *bAh = (l & 1) ? P0h : Qh, *bAl = (l & 1) ? P0l : Ql;  // q_{l-1} / r1_{l+1}
      {  // VNEW: v = (r2 + 0.1 r1@Wp + r2@E)/11 -> Vh ; s2(l) -> S2 ; p -> Ph
        Ep e{};
        e.Ah = bCh; e.Bh = WpTh + lz; e.Bl = WpTl + lz;
        e.A2 = R2h; e.B2 = E32 + lz;
        e.x0h = R2h; e.x0l = R2l;
        e.x1s = Vh;
        e.x2h = S2h; e.x2l = S2l;
        e.x3h = bAh; e.x3l = bAl;
        e.ov = Vh; e.op = Ph; e.o1h = S2h; e.o1l = S2l;
        e.sAi = 1.f / (32.f * sl); e.sSi = 1.f / sl;
        e.sPi = l ? 1.f / SIG[l - 1] : 0.f; e.sO = sl;
        e.dos2 = l ? 1 : 0; e.Mh = 1 << 30;
        gk<MVN><<<gg, 256, 0, stream>>>(e);
      }
      if (l < 3) {
        {  // U: q = 10*(0.1 r1) - 0.1 v@W^T + s1 -> in-place over r1
          Ep e{};
          e.Ah = Vh; e.Bh = Wh + lz; e.Bl = Wl + lz;
          e.x0h = bCh; e.x0l = bCl; e.rf0 = S1;
          e.o0h = bCh; e.o0l = bCl;
          e.sAi = 1.f / (32.f * sl); e.sSi = 1.f / sl; e.sO = sl;
          e.Mh = 1 << 30;
          gk<MU><<<gg, 256, 0, stream>>>(e);
        }
        {  // QP: q-half q@W -> r2' ; p-half p@W^T -> s1', r1'
          Ep e{};
          e.Ah = bCh; e.Bh = WTh + lz; e.Bl = WTl + lz;
          e.Ch = Ph; e.Dh = Wh + lz; e.Dl = Wl + lz;
          e.x0h = bCh; e.x0l = bCl;
          e.x1s = Vh;
          e.x2h = S2h; e.x2l = S2l;
          e.rf0 = S1; e.of = S1;
          e.o0h = R2h; e.o0l = R2l;    // r2'
          e.o1h = bAh; e.o1l = bAl;    // 0.1*r1'
          e.bias2 = bl[l + 1];
          e.sAi = 1.f / (32.f * sl); e.sSi = 1.f / sl; e.sO2 = SIG[l + 1];
          e.Mh = Mc;
          gk<MQP><<<gg2, 256, 0, stream>>>(e);
        }
      } else {  // UL: logits = -(10*(0.1 r1) - 0.1 v@W^T + s1) -> R2 pair (scale 1)
        Ep e{};
        e.Ah = Vh; e.Bh = Wh + lz; e.Bl = Wl + lz;
        e.x0h = bCh; e.x0l = bCl; e.rf0 = S1;
        e.o0h = R2h; e.o0l = R2l;
        e.sAi = 1.f / (32.f * sl); e.sSi = 1.f / sl; e.sO = 1.f;
        e.Mh = 1 << 30;
        gk<MUL><<<gg, 256, 0, stream>>>(e);
      }
    }
    out_softmax<<<dim3(Mc / 4), 256, 0, stream>>>(R2h, R2l, Wout, bout, out + r0 * 10);
  }
}

// Round 14
// 1279.670 us; speedup vs baseline: 1.3105x; 1.2075x over previous
//
#include <hip/hip_runtime.h>

typedef _Float16 f16;
typedef _Float16 f16x8 __attribute__((ext_vector_type(8)));
typedef _Float16 f16x4 __attribute__((ext_vector_type(4)));
typedef float f32x4 __attribute__((ext_vector_type(4)));

#define GLD(g, l) __builtin_amdgcn_global_load_lds( \
    (const __attribute__((address_space(1))) void*)(g), \
    (__attribute__((address_space(3))) void*)(l), 16, 0, 0)

enum { MZ0, MVN, MU, MUL, MQP, MG, ME, MWP };

struct Ep {
  const f16 *Ah, *Bh, *Bl;       // primary A (1 plane); B hi (+ lo only for Z0)
  const f16 *A2, *B2;            // VNEW pass 1: r2h @ E32
  const f16 *Ch, *Dh;            // QP p-half: ph @ Wh
  f16 *o0h, *o0l, *o1h, *o1l, *o2h, *o2l;
  f16 *ov, *op;                  // single-plane outs (v, p)
  float* of;
  const f16 *x0h, *x0l, *x2h, *x2l, *x3h, *x3l;
  const f16* x1s;                // single-plane read (v)
  const float* rf0;
  const float *w0, *w1, *w2, *w3;
  const float *bias, *bias2;
  float sAi, sSi, sPi, sO, sO2;
  int Mh, dos2;
  size_t zA, zB, zO;
};

__device__ __forceinline__ float rec2(const f16* h, const f16* l, size_t i) {
  return (float)h[i] + (float)l[i];
}
__device__ __forceinline__ void wp2(f16* h, f16* l, size_t i, float v) {
  const f16 hi = (f16)v;
  h[i] = hi;
  l[i] = (f16)(v - (float)hi);
}

// C = sum_passes A_p @ B_p^T; 64x128 tiles, BK=32, 4 waves (2x2: 2 m-frags x 4 n-frags).
// NP=1 {A@B0}. NP=2: MZ0 {x@Winh, x@Winl}; MVN {r1@Wp, r2@E} (pass 1 has own A).
// B-lo planes dropped everywhere except Z0 (all other GEMM outputs are 0.1-damped).
// Rotated K-loop (stage next step under MFMA) + chunked XCD swizzle (XCD owns tm band).
template <int MODE>
__global__ __launch_bounds__(256, 4) void gk(Ep ep) {
  constexpr bool P2A = (MODE == MVN);  // pass 1 uses its own A (r2@E)
  constexpr int NP = (MODE == MZ0 || MODE == MVN) ? 2 : 1;
  __shared__ f16 SA0[2048] __attribute__((aligned(16)));
  __shared__ f16 SB0[4096] __attribute__((aligned(16)));
  __shared__ f16 SA1[P2A ? 2048 : 16] __attribute__((aligned(16)));
  __shared__ f16 SB1[NP == 2 ? 4096 : 16] __attribute__((aligned(16)));
  const int tid = threadIdx.x;
  const int w = tid >> 6, lane = tid & 63;
  const unsigned nb = gridDim.x;
  const unsigned bid = blockIdx.x;
  const unsigned swz = (bid & 7) * (nb >> 3) + (bid >> 3);  // bijective, nb%8==0
  const int tn = (int)(swz & 7) * 128;
  const int tm = (int)(swz >> 3) * 64;
  const int ly = blockIdx.y;
  const size_t zoA = (size_t)ly * ep.zA;
  const size_t zoB = (size_t)ly * ep.zB;
  const size_t zoO = (size_t)ly * ep.zO;

  const bool half2 = (MODE == MQP) && (tm >= ep.Mh);
  const int tmr = half2 ? tm - ep.Mh : tm;

  const f16* pA0 = half2 ? ep.Ch : ep.Ah;
  const f16* pB0 = half2 ? ep.Dh : ep.Bh;

  const int srow = w * 16 + (lane >> 2);  // 0..63
  const int scol = (lane & 3) * 8;
  const size_t aoff = zoA + (size_t)(tmr + srow) * 1024 + scol;
  const size_t boff = zoB + (size_t)(tn + srow) * 1024 + scol;
  const f16* gA0 = pA0 + aoff;
  const f16* gB0 = pB0 + boff;
  const f16* gA1 = P2A ? ep.A2 + aoff : pA0 + aoff;
  const f16* gB1 = (NP == 2) ? ((MODE == MZ0) ? ep.Bl + boff : ep.B2 + boff) : pB0 + boff;

  const int wr = w >> 1, wc = w & 1;
  const int fr = lane & 15;
  const int kb = (lane >> 4) * 8;
  const int ao = (wr * 32 + fr) * 32 + kb;
  const int bo = (wc * 64 + fr) * 32 + kb;

  auto stage = [&](int kt) {
    GLD(gA0 + kt, SA0 + w * 512);
    GLD(gB0 + kt, SB0 + w * 512); GLD(gB0 + kt + 65536, SB0 + 2048 + w * 512);
    if constexpr (P2A) GLD(gA1 + kt, SA1 + w * 512);
    if constexpr (NP == 2) {
      GLD(gB1 + kt, SB1 + w * 512); GLD(gB1 + kt + 65536, SB1 + 2048 + w * 512);
    }
  };

  f32x4 acc[2][4] = {};
  stage(0);

  for (int kt = 0; kt < 1024; kt += 32) {
    __syncthreads();  // staged GLDs complete
    f16x8 a0[2], a1[2], b0[4], b1[4];
#pragma unroll
    for (int i = 0; i < 2; i++) a0[i] = *(const f16x8*)(SA0 + ao + i * 512);
#pragma unroll
    for (int i = 0; i < 4; i++) b0[i] = *(const f16x8*)(SB0 + bo + i * 512);
    if constexpr (P2A) {
#pragma unroll
      for (int i = 0; i < 2; i++) a1[i] = *(const f16x8*)(SA1 + ao + i * 512);
    }
    if constexpr (NP == 2) {
#pragma unroll
      for (int i = 0; i < 4; i++) b1[i] = *(const f16x8*)(SB1 + bo + i * 512);
    }
    __syncthreads();  // all waves done reading LDS
    if (kt < 992) stage(kt + 32);  // next-step loads fly under MFMA

    auto mm = [&](f16x8 (&fa)[2], f16x8 (&fb)[4]) {
#pragma unroll
      for (int mi = 0; mi < 2; mi++)
#pragma unroll
        for (int ni = 0; ni < 4; ni++)
          acc[mi][ni] = __builtin_amdgcn_mfma_f32_16x16x32_f16(fa[mi], fb[ni], acc[mi][ni], 0, 0, 0);
    };
    mm(a0, b0);
    if constexpr (MODE == MZ0) mm(a0, b1);
    if constexpr (MODE == MVN) mm(a1, b1);
  }

  // C/D layout: col = lane&15, row = (lane>>4)*4 + j
  const int er = wr * 32 + ((lane >> 4) << 2);
  const int ec = wc * 64 + fr;
#pragma unroll
  for (int mi = 0; mi < 2; mi++)
#pragma unroll
    for (int ni = 0; ni < 4; ni++)
#pragma unroll
      for (int j = 0; j < 4; j++) {
        const int r = tmr + er + mi * 16 + j;
        const int c = tn + ec + ni * 16;
        const size_t i = (size_t)r * 1024 + c;
        const float av = acc[mi][ni][j];
        if constexpr (MODE == MZ0) {
          const float z = av * ep.sAi + ep.bias[c];
          wp2(ep.o0h, ep.o0l, i, 0.1f * (z + 0.1f * ep.bias2[c]) * ep.sO);  // 0.1*r1*SIG
          wp2(ep.o1h, ep.o1l, i, 11.f * fmaxf(z, 0.f) * ep.sO);            // r2*SIG
          wp2(ep.o2h, ep.o2l, i, 0.f);                                     // s2 = 0
          ep.of[i] = 0.f;                                                  // s1 = 0
        } else if constexpr (MODE == MVN) {
          const float G = av * ep.sAi;                  // 0.1*r1@Wp + r2@E
          const float r2 = rec2(ep.x0h, ep.x0l, i) * ep.sSi;
          const float v = (r2 + G) * (1.f / 11.f);
          float s2n = 0.f;
          if (ep.dos2) {
            const float s2o = rec2(ep.x2h, ep.x2l, i) * ep.sPi;
            const float vo = (float)ep.x1s[i] * ep.sPi;
            const float qo = rec2(ep.x3h, ep.x3l, i) * ep.sPi;
            s2n = -r2 - s2o - vo + 10.f * fmaxf(-qo, 0.f);
            wp2(ep.o1h, ep.o1l, i, s2n * ep.sO);        // s2(l)
          }
          ep.ov[i] = (f16)(v * ep.sO);                  // v (after reading old v)
          ep.op[i] = (f16)((v + s2n) * ep.sO);          // p = v + s2
        } else if constexpr (MODE == MU || MODE == MUL) {
          const float vW = av * ep.sAi;
          const float r1 = rec2(ep.x0h, ep.x0l, i) * ep.sSi * 10.f;
          const float q = r1 - 0.1f * vW + ep.rf0[i];
          if constexpr (MODE == MU)
            wp2(ep.o0h, ep.o0l, i, q * ep.sO);          // q in-place over r1
          else
            wp2(ep.o0h, ep.o0l, i, -q);                 // logits (scale 1)
        } else if constexpr (MODE == MQP) {
          if (!half2) {
            const float qW = av * ep.sAi;
            const float v = (float)ep.x1s[i] * ep.sSi;
            const float s2 = rec2(ep.x2h, ep.x2l, i) * ep.sSi;
            const float qq = rec2(ep.x0h, ep.x0l, i) * ep.sSi;
            wp2(ep.o0h, ep.o0l, i,
                (10.f * v + 9.f * s2 + 10.f * fmaxf(-qq, 0.f) - 0.1f * qW) * ep.sO2);  // r2'
          } else {
            const float pW = av * ep.sAi;
            const float s1 = ep.rf0[i];
            const float qq = rec2(ep.x0h, ep.x0l, i) * ep.sSi;
            ep.of[i] = -(qq - s1) - 0.1f * pW;                                          // s1'
            wp2(ep.o1h, ep.o1l, i, 0.1f * (0.1f * ep.bias2[c] - s1 + 0.1f * pW) * ep.sO2);  // 0.1*r1'
          }
        } else if constexpr (MODE == MG) {
          const float gv = av * (1.f / 1024.f);
          ep.of[zoO + i] = gv;
          ep.o0h[zoO + i] = (f16)gv;
        } else if constexpr (MODE == ME) {
          constexpr float C1 = 0.01f / 11.f;
          ep.o0h[zoO + i] = (f16)(32.f * (C1 * C1 * av - C1 * ep.rf0[zoO + i]));
        } else if constexpr (MODE == MWP) {
          const float* Wf = ly == 0 ? ep.w0 : ly == 1 ? ep.w1 : ly == 2 ? ep.w2 : ep.w3;
          ep.o0h[zoO + i] = (f16)(32.f * (Wf[(size_t)c * 1024 + r] + av * (1.f / 1024.f)));  // WpT hi
        }
      }
}

template <int MC>
__global__ void mcprobe() {}  // Mc diagnostic

// x: pad 784->1024, x16, hi plane only
__global__ __launch_bounds__(256) void xstage(const float* __restrict__ src,
                                              f16* __restrict__ h) {
  const size_t i = (size_t)blockIdx.x * 256 + threadIdx.x;
  const int k = (int)(i & 1023);
  const size_t m = i >> 10;
  h[i] = (f16)((k < 784) ? 16.f * src[m * 784 + k] : 0.f);
}

// Win: pad 784->1024, x32 split (z is undamped -> keep Win exact-ish)
__global__ __launch_bounds__(256) void winstage(const float* __restrict__ src,
                                                f16* __restrict__ h, f16* __restrict__ l) {
  const size_t i = (size_t)blockIdx.x * 256 + threadIdx.x;
  const int k = (int)(i & 1023);
  const size_t m = i >> 10;
  const float s = (k < 784) ? 32.f * src[m * 784 + k] : 0.f;
  const f16 hi = (f16)s;
  h[i] = hi;
  l[i] = (f16)(s - (float)hi);
}

// 4 layer weights -> x32 hi planes, direct + transposed
__global__ __launch_bounds__(256) void wstage(const float* __restrict__ W0, const float* __restrict__ W1,
                                              const float* __restrict__ W2, const float* __restrict__ W3,
                                              f16* __restrict__ Wh, f16* __restrict__ WTh) {
  __shared__ float t[32][33];
  const int lz = blockIdx.z;
  const float* W = lz == 0 ? W0 : lz == 1 ? W1 : lz == 2 ? W2 : W3;
  const size_t off = (size_t)lz * 1024 * 1024;
  const int c0 = blockIdx.x * 32, r0 = blockIdx.y * 32;
  const int tx = threadIdx.x, ty = threadIdx.y;
#pragma unroll
  for (int i = ty; i < 32; i += 8) {
    const float v = W[(size_t)(r0 + i) * 1024 + c0 + tx];
    t[i][tx] = v;
    Wh[off + (size_t)(r0 + i) * 1024 + c0 + tx] = (f16)(32.f * v);
  }
  __syncthreads();
#pragma unroll
  for (int i = ty; i < 32; i += 8)
    WTh[off + (size_t)(c0 + i) * 1024 + r0 + tx] = (f16)(32.f * t[tx][i]);
}

// logits = softmax(rec(L) @ Wout^T + bout); one wave per row
__global__ __launch_bounds__(256) void out_softmax(const f16* __restrict__ Lh, const f16* __restrict__ Ll,
                                                   const float* __restrict__ Wout,
                                                   const float* __restrict__ bo,
                                                   float* __restrict__ out) {
  const int row = blockIdx.x * 4 + (threadIdx.x >> 6);
  const int lane = threadIdx.x & 63;
  const size_t rb = (size_t)row * 1024;
  float p[10];
#pragma unroll
  for (int t = 0; t < 10; t++) p[t] = 0.f;
#pragma unroll
  for (int j = 0; j < 4; j++) {
    const int kbase = (j * 64 + lane) * 4;
    const f16x4 hv = *(const f16x4*)(Lh + rb + kbase);
    const f16x4 lv = *(const f16x4*)(Ll + rb + kbase);
    float uv[4];
#pragma unroll
    for (int e = 0; e < 4; e++) uv[e] = (float)hv[e] + (float)lv[e];
#pragma unroll
    for (int t = 0; t < 10; t++) {
      const float4 wv = *(const float4*)(Wout + t * 1024 + kbase);
      p[t] += uv[0] * wv.x + uv[1] * wv.y + uv[2] * wv.z + uv[3] * wv.w;
    }
  }
#pragma unroll
  for (int off = 32; off; off >>= 1)
#pragma unroll
    for (int t = 0; t < 10; t++) p[t] += __shfl_down(p[t], off);
  if (lane == 0) {
    float lg[10], m = -1e30f, s = 0.f;
#pragma unroll
    for (int t = 0; t < 10; t++) { lg[t] = p[t] + bo[t]; m = fmaxf(m, lg[t]); }
#pragma unroll
    for (int t = 0; t < 10; t++) { lg[t] = expf(lg[t] - m); s += lg[t]; }
    const float inv = 1.f / s;
    float* o = out + (size_t)row * 10;
#pragma unroll
    for (int t = 0; t < 10; t++) o[t] = lg[t] * inv;
  }
}

extern "C" void kernel_launch(void* const* d_in, const int* in_sizes, int n_in,
                              void* d_out, int out_size, void* d_ws, size_t ws_size,
                              hipStream_t stream) {
  const float* x = (const float*)d_in[0];
  const float* Win = (const float*)d_in[1];
  const float* bin = (const float*)d_in[2];
  const float* Wgt[4] = {(const float*)d_in[3], (const float*)d_in[5],
                         (const float*)d_in[7], (const float*)d_in[9]};
  const float* bl[4] = {(const float*)d_in[4], (const float*)d_in[6],
                        (const float*)d_in[8], (const float*)d_in[10]};
  const float* Wout = (const float*)d_in[11];
  const float* bout = (const float*)d_in[12];
  float* out = (float*)d_out;

  char* p = (char*)d_ws;
  auto take = [&](size_t n) {
    void* q = (void*)p;
    p += (n + 255) & ~(size_t)255;
    return q;
  };
  const size_t UM = (size_t)1024 * 1024;

  // weights (~36MB)
  f16* Winh = (f16*)take(UM * 2);
  f16* Winl = (f16*)take(UM * 2);
  f16* Wh = (f16*)take(4 * UM * 2);
  f16* WTh = (f16*)take(4 * UM * 2);
  f16* WpTh = (f16*)take(4 * UM * 2);
  f16* E32 = (f16*)take(4 * UM * 2);
  const size_t fixedB = (size_t)(p - (char*)d_ws);

  int Mc = 8192;
  auto actB = [&](int m) {
    size_t a = (size_t)m * 1024 * 24;  // 10 f16 planes + 1 f32
    if (m < 4096) a += 24 * UM;        // dedicated G scratch
    return a;
  };
  while (Mc > 1024 && fixedB + actB(Mc) + 65536 > ws_size) Mc >>= 1;
  if (fixedB + actB(Mc) + 65536 > ws_size) return;
  const size_t CF = (size_t)Mc * 1024;

  f16* P0h = (f16*)take(CF * 2); f16* P0l = (f16*)take(CF * 2);
  f16* Qh = (f16*)take(CF * 2);  f16* Ql = (f16*)take(CF * 2);
  f16* R2h = (f16*)take(CF * 2); f16* R2l = (f16*)take(CF * 2);
  f16* S2h = (f16*)take(CF * 2); f16* S2l = (f16*)take(CF * 2);
  f16* Vh = (f16*)take(CF * 2);
  f16* Ph = (f16*)take(CF * 2);
  float* S1 = (float*)take(CF * 4);
  float* Gf;
  f16* Gh;
  if (Mc >= 4096) {    // alias precompute scratch over act planes (dead then)
    Gf = (float*)P0h;  // 16MB over P0h+P0l
    Gh = (f16*)Qh;     // 8MB over Qh
  } else {
    Gf = (float*)take(4 * UM * 4);
    Gh = (f16*)take(4 * UM * 2);
  }

  switch (Mc) {
    case 8192: mcprobe<8><<<1, 1, 0, stream>>>(); break;
    case 4096: mcprobe<4><<<1, 1, 0, stream>>>(); break;
    case 2048: mcprobe<2><<<1, 1, 0, stream>>>(); break;
    default:   mcprobe<1><<<1, 1, 0, stream>>>(); break;
  }

  // ---- weight precompute (batched over 4 layers via blockIdx.y) ----
  winstage<<<dim3((unsigned)(UM / 256)), 256, 0, stream>>>(Win, Winh, Winl);
  wstage<<<dim3(32, 32, 4), dim3(32, 8), 0, stream>>>(Wgt[0], Wgt[1], Wgt[2], Wgt[3],
                                                      Wh, WTh);
  {  // G = W^T W (hi-only)
    Ep e{};
    e.Ah = WTh; e.Bh = WTh;
    e.zA = UM; e.zB = UM; e.zO = UM;
    e.of = Gf; e.o0h = Gh;
    gk<MG><<<dim3(128, 4), 256, 0, stream>>>(e);
  }
  {  // E32 = 32*(c^2 G^2 - c G)
    Ep e{};
    e.Ah = Gh; e.Bh = Gh; e.zA = UM; e.zB = UM; e.zO = UM;
    e.rf0 = Gf; e.o0h = E32;
    gk<ME><<<dim3(128, 4), 256, 0, stream>>>(e);
  }
  {  // WpT = W^T + E @ W^T (hi plane)
    Ep e{};
    e.Ah = E32; e.Bh = Wh; e.zA = UM; e.zB = UM; e.zO = UM;
    e.w0 = Wgt[0]; e.w1 = Wgt[1]; e.w2 = Wgt[2]; e.w3 = Wgt[3];
    e.o0h = WpTh;
    gk<MWP><<<dim3(128, 4), 256, 0, stream>>>(e);
  }

  const float SIG[5] = {16.f, 2.f, 0.25f, 0.03125f, 1.f};
  const int nch = 8192 / Mc;
  const dim3 gg((unsigned)(Mc / 64) * 8);
  const dim3 gg2((unsigned)(Mc / 64) * 16);

  for (int ch = 0; ch < nch; ++ch) {
    const size_t r0 = (size_t)ch * Mc;
    xstage<<<dim3(Mc * 4), 256, 0, stream>>>(x + r0 * 784, Qh);
    {  // Z0: z = x@Win^T + b_in -> P0 (0.1*r1), R2, S2=0, S1=0
      Ep e{};
      e.Ah = Qh; e.Bh = Winh; e.Bl = Winl;
      e.bias = bin; e.bias2 = bl[0];
      e.o0h = P0h; e.o0l = P0l; e.o1h = R2h; e.o1l = R2l; e.o2h = S2h; e.o2l = S2l;
      e.of = S1; e.sAi = 1.f / 512.f; e.sO = 16.f;
      e.Mh = 1 << 30;
      gk<MZ0><<<gg, 256, 0, stream>>>(e);
    }
    for (int l = 0; l < 4; l++) {
      const size_t lz = (size_t)l * UM;
      const float sl = SIG[l];
      f16 *bCh = (l & 1) ? Qh : P0h, *bCl = (l & 1) ? Ql : P0l;  // r1_l -> q_l
      f16 *bAh = (l & 1) ? P0h : Qh, *bAl = (l & 1) ? P0l : Ql;  // q_{l-1} / r1_{l+1}
      {  // VNEW: v = (r2 + 0.1 r1@Wp + r2@E)/11 -> Vh ; s2(l) -> S2 ; p -> Ph
        Ep e{};
        e.Ah = bCh; e.Bh = WpTh + lz;
        e.A2 = R2h; e.B2 = E32 + lz;
        e.x0h = R2h; e.x0l = R2l;
        e.x1s = Vh;
        e.x2h = S2h; e.x2l = S2l;
        e.x3h = bAh; e.x3l = bAl;
        e.ov = Vh; e.op = Ph; e.o1h = S2h; e.o1l = S2l;
        e.sAi = 1.f / (32.f * sl); e.sSi = 1.f / sl;
        e.sPi = l ? 1.f / SIG[l - 1] : 0.f; e.sO = sl;
        e.dos2 = l ? 1 : 0; e.Mh = 1 << 30;
        gk<MVN><<<gg, 256, 0, stream>>>(e);
      }
      if (l < 3) {
        {  // U: q = 10*(0.1 r1) - 0.1 v@W^T + s1 -> in-place over r1
          Ep e{};
          e.Ah = Vh; e.Bh = Wh + lz;
          e.x0h = bCh; e.x0l = bCl; e.rf0 = S1;
          e.o0h = bCh; e.o0l = bCl;
          e.sAi = 1.f / (32.f * sl); e.sSi = 1.f / sl; e.sO = sl;
          e.Mh = 1 << 30;
          gk<MU><<<gg, 256, 0, stream>>>(e);
        }
        {  // QP: q-half q@W -> r2' ; p-half p@W^T -> s1', r1'
          Ep e{};
          e.Ah = bCh; e.Bh = WTh + lz;
          e.Ch = Ph; e.Dh = Wh + lz;
          e.x0h = bCh; e.x0l = bCl;
          e.x1s = Vh;
          e.x2h = S2h; e.x2l = S2l;
          e.rf0 = S1; e.of = S1;
          e.o0h = R2h; e.o0l = R2l;    // r2'
          e.o1h = bAh; e.o1l = bAl;    // 0.1*r1'
          e.bias2 = bl[l + 1];
          e.sAi = 1.f / (32.f * sl); e.sSi = 1.f / sl; e.sO2 = SIG[l + 1];
          e.Mh = Mc;
          gk<MQP><<<gg2, 256, 0, stream>>>(e);
        }
      } else {  // UL: logits = -(10*(0.1 r1) - 0.1 v@W^T + s1) -> R2 pair (scale 1)
        Ep e{};
        e.Ah = Vh; e.Bh = Wh + lz;
        e.x0h = bCh; e.x0l = bCl; e.rf0 = S1;
        e.o0h = R2h; e.o0l = R2l;
        e.sAi = 1.f / (32.f * sl); e.sSi = 1.f / sl; e.sO = 1.f;
        e.Mh = 1 << 30;
        gk<MUL><<<gg, 256, 0, stream>>>(e);
      }
    }
    out_softmax<<<dim3(Mc / 4), 256, 0, stream>>>(R2h, R2l, Wout, bout, out + r0 * 10);
  }
}

// Round 17
// 1092.431 us; speedup vs baseline: 1.5352x; 1.1714x over previous
//
#include <hip/hip_runtime.h>

typedef _Float16 f16;
typedef _Float16 f16x8 __attribute__((ext_vector_type(8)));
typedef _Float16 f16x4 __attribute__((ext_vector_type(4)));
typedef float f32x4 __attribute__((ext_vector_type(4)));

#define GLD(g, l) __builtin_amdgcn_global_load_lds( \
    (const __attribute__((address_space(1))) void*)(g), \
    (__attribute__((address_space(3))) void*)(l), 16, 0, 0)

enum { MZ0, MVN, MU, MUL, MQP, MG, ME, MWP };

struct Ep {
  const f16 *Ah, *Bh, *Bl;       // primary A (1 plane); B hi (+ lo only for Z0)
  const f16 *A2, *B2;            // VNEW pass 1: r2h @ E32
  const f16 *Ch, *Dh;            // QP p-half: ph @ Wh
  f16 *o0h, *o0l, *o1h, *o1l, *o2h, *o2l;
  f16 *ov, *op;                  // single-plane outs (v, p)
  float* of;
  const f16 *x0h, *x0l, *x2h, *x2l, *x3h, *x3l;
  const f16* x1s;                // single-plane read (v)
  const float* rf0;
  const float *w0, *w1, *w2, *w3;
  const float *bias, *bias2;
  float sAi, sSi, sPi, sO, sO2;
  int Mh, dos2;
  size_t zA, zB, zO;
};

__device__ __forceinline__ float rec2(const f16* h, const f16* l, size_t i) {
  return (float)h[i] + (float)l[i];
}
__device__ __forceinline__ void wp2(f16* h, f16* l, size_t i, float v) {
  const f16 hi = (f16)v;
  h[i] = hi;
  l[i] = (f16)(v - (float)hi);
}

// ---- 8-wide vector helpers (MQP-only experiment) ----
__device__ __forceinline__ void ld_pair8(const f16* h, const f16* l, size_t i, float s, float* o) {
  const f16x8 hv = *(const f16x8*)(h + i);
  const f16x8 lv = *(const f16x8*)(l + i);
#pragma unroll
  for (int e = 0; e < 8; e++) o[e] = ((float)hv[e] + (float)lv[e]) * s;
}
__device__ __forceinline__ void ld_s8(const f16* p, size_t i, float s, float* o) {
  const f16x8 hv = *(const f16x8*)(p + i);
#pragma unroll
  for (int e = 0; e < 8; e++) o[e] = (float)hv[e] * s;
}
__device__ __forceinline__ void ld_f8(const float* p, size_t i, float* o) {
  const float4 a = *(const float4*)(p + i);
  const float4 b = *(const float4*)(p + i + 4);
  o[0] = a.x; o[1] = a.y; o[2] = a.z; o[3] = a.w;
  o[4] = b.x; o[5] = b.y; o[6] = b.z; o[7] = b.w;
}
__device__ __forceinline__ void st_pair8(f16* h, f16* l, size_t i, const float* v, float s) {
  f16x8 hv, lv;
#pragma unroll
  for (int e = 0; e < 8; e++) {
    const float x = v[e] * s;
    const f16 hi = (f16)x;
    hv[e] = hi;
    lv[e] = (f16)(x - (float)hi);
  }
  *(f16x8*)(h + i) = hv;
  *(f16x8*)(l + i) = lv;
}
__device__ __forceinline__ void st_f8(float* p, size_t i, const float* v) {
  *(float4*)(p + i) = make_float4(v[0], v[1], v[2], v[3]);
  *(float4*)(p + i + 4) = make_float4(v[4], v[5], v[6], v[7]);
}

// C = sum_passes A_p @ B_p^T; 64x128 tiles, BK=32, 4 waves (2x2: 2 m-frags x 4 n-frags).
// NP=1 {A@B0}. NP=2: MZ0 {x@Winh, x@Winl}; MVN {r1@Wp, r2@E}. B-lo only for Z0.
// Rotated K-loop (stage next step under MFMA) + chunked XCD swizzle.
// Epilogue: r14-verified scalar path everywhere EXCEPT MQP, which uses a separate
// (non-aliased) [64][132] f32 LDS image + coalesced f16x8/float4 vector state ops.
template <int MODE>
__global__ __launch_bounds__(256, 4) void gk(Ep ep) {
  constexpr bool P2A = (MODE == MVN);  // pass 1 uses its own A (r2@E)
  constexpr int NP = (MODE == MZ0 || MODE == MVN) ? 2 : 1;
  constexpr bool VQ = (MODE == MQP);   // vector-epilogue experiment: MQP only
  __shared__ f16 SA0[2048] __attribute__((aligned(16)));
  __shared__ f16 SB0[4096] __attribute__((aligned(16)));
  __shared__ f16 SA1[P2A ? 2048 : 16] __attribute__((aligned(16)));
  __shared__ f16 SB1[NP == 2 ? 4096 : 16] __attribute__((aligned(16)));
  __shared__ float EPI[VQ ? 64 * 132 : 4] __attribute__((aligned(16)));
  const int tid = threadIdx.x;
  const int w = tid >> 6, lane = tid & 63;
  const unsigned nb = gridDim.x;
  const unsigned bid = blockIdx.x;
  const unsigned swz = (bid & 7) * (nb >> 3) + (bid >> 3);  // bijective, nb%8==0
  const int tn = (int)(swz & 7) * 128;
  const int tm = (int)(swz >> 3) * 64;
  const int ly = blockIdx.y;
  const size_t zoA = (size_t)ly * ep.zA;
  const size_t zoB = (size_t)ly * ep.zB;
  const size_t zoO = (size_t)ly * ep.zO;

  const bool half2 = (MODE == MQP) && (tm >= ep.Mh);
  const int tmr = half2 ? tm - ep.Mh : tm;

  const f16* pA0 = half2 ? ep.Ch : ep.Ah;
  const f16* pB0 = half2 ? ep.Dh : ep.Bh;

  const int srow = w * 16 + (lane >> 2);  // 0..63
  const int scol = (lane & 3) * 8;
  const size_t aoff = zoA + (size_t)(tmr + srow) * 1024 + scol;
  const size_t boff = zoB + (size_t)(tn + srow) * 1024 + scol;
  const f16* gA0 = pA0 + aoff;
  const f16* gB0 = pB0 + boff;
  const f16* gA1 = P2A ? ep.A2 + aoff : pA0 + aoff;
  const f16* gB1 = (NP == 2) ? ((MODE == MZ0) ? ep.Bl + boff : ep.B2 + boff) : pB0 + boff;

  const int wr = w >> 1, wc = w & 1;
  const int fr = lane & 15;
  const int kb = (lane >> 4) * 8;
  const int ao = (wr * 32 + fr) * 32 + kb;
  const int bo = (wc * 64 + fr) * 32 + kb;

  auto stage = [&](int kt) {
    GLD(gA0 + kt, SA0 + w * 512);
    GLD(gB0 + kt, SB0 + w * 512); GLD(gB0 + kt + 65536, SB0 + 2048 + w * 512);
    if constexpr (P2A) GLD(gA1 + kt, SA1 + w * 512);
    if constexpr (NP == 2) {
      GLD(gB1 + kt, SB1 + w * 512); GLD(gB1 + kt + 65536, SB1 + 2048 + w * 512);
    }
  };

  f32x4 acc[2][4] = {};
  stage(0);

  for (int kt = 0; kt < 1024; kt += 32) {
    __syncthreads();  // staged GLDs complete
    f16x8 a0[2], a1[2], b0[4], b1[4];
#pragma unroll
    for (int i = 0; i < 2; i++) a0[i] = *(const f16x8*)(SA0 + ao + i * 512);
#pragma unroll
    for (int i = 0; i < 4; i++) b0[i] = *(const f16x8*)(SB0 + bo + i * 512);
    if constexpr (P2A) {
#pragma unroll
      for (int i = 0; i < 2; i++) a1[i] = *(const f16x8*)(SA1 + ao + i * 512);
    }
    if constexpr (NP == 2) {
#pragma unroll
      for (int i = 0; i < 4; i++) b1[i] = *(const f16x8*)(SB1 + bo + i * 512);
    }
    __syncthreads();  // all waves done reading LDS
    if (kt < 992) stage(kt + 32);  // next-step loads fly under MFMA

    auto mm = [&](f16x8 (&fa)[2], f16x8 (&fb)[4]) {
#pragma unroll
      for (int mi = 0; mi < 2; mi++)
#pragma unroll
        for (int ni = 0; ni < 4; ni++)
          acc[mi][ni] = __builtin_amdgcn_mfma_f32_16x16x32_f16(fa[mi], fb[ni], acc[mi][ni], 0, 0, 0);
    };
    mm(a0, b0);
    if constexpr (MODE == MZ0) mm(a0, b1);
    if constexpr (MODE == MVN) mm(a1, b1);
  }

  if constexpr (VQ) {
    // MQP vectorized epilogue: separate EPI buffer, unguarded full-tile write
    __syncthreads();
    {
      const int er = wr * 32 + ((lane >> 4) << 2);
      const int ec = wc * 64 + fr;
#pragma unroll
      for (int mi = 0; mi < 2; mi++)
#pragma unroll
        for (int ni = 0; ni < 4; ni++)
#pragma unroll
          for (int j = 0; j < 4; j++)
            EPI[(er + mi * 16 + j) * 132 + ec + ni * 16] = acc[mi][ni][j];
    }
    __syncthreads();
#pragma unroll
    for (int t = 0; t < 4; ++t) {
      const int rl = (tid >> 4) + t * 16;  // 0..63
      const int c8 = (tid & 15) * 8;       // 0..120
      const int r = tmr + rl;
      const int c0 = tn + c8;
      const size_t i = (size_t)r * 1024 + c0;
      float av[8];
      {
        const f32x4 q0 = *(const f32x4*)(EPI + rl * 132 + c8);
        const f32x4 q1 = *(const f32x4*)(EPI + rl * 132 + c8 + 4);
#pragma unroll
        for (int e = 0; e < 4; e++) { av[e] = q0[e]; av[4 + e] = q1[e]; }
      }
      if (!half2) {
        float qq[8], vv[8], s2[8], o[8];
        ld_pair8(ep.x0h, ep.x0l, i, ep.sSi, qq);
        ld_s8(ep.x1s, i, ep.sSi, vv);
        ld_pair8(ep.x2h, ep.x2l, i, ep.sSi, s2);
#pragma unroll
        for (int e = 0; e < 8; e++)
          o[e] = 10.f * vv[e] + 9.f * s2[e] + 10.f * fmaxf(-qq[e], 0.f)
                 - 0.1f * (av[e] * ep.sAi);
        st_pair8(ep.o0h, ep.o0l, i, o, ep.sO2);          // r2'
      } else {
        float qq[8], s1v[8], bib[8], s1o[8], r1n[8];
        ld_pair8(ep.x0h, ep.x0l, i, ep.sSi, qq);
        ld_f8(ep.rf0, i, s1v);
        ld_f8(ep.bias2, c0, bib);
#pragma unroll
        for (int e = 0; e < 8; e++) {
          const float pW = av[e] * ep.sAi;
          s1o[e] = -(qq[e] - s1v[e]) - 0.1f * pW;
          r1n[e] = 0.1f * (0.1f * bib[e] - s1v[e] + 0.1f * pW);
        }
        st_f8(ep.of, i, s1o);                            // s1'
        st_pair8(ep.o1h, ep.o1l, i, r1n, ep.sO2);        // 0.1*r1'
      }
    }
  } else {
    // r14-verified scalar epilogue (all other modes)
    const int er = wr * 32 + ((lane >> 4) << 2);
    const int ec = wc * 64 + fr;
#pragma unroll
    for (int mi = 0; mi < 2; mi++)
#pragma unroll
      for (int ni = 0; ni < 4; ni++)
#pragma unroll
        for (int j = 0; j < 4; j++) {
          const int r = tmr + er + mi * 16 + j;
          const int c = tn + ec + ni * 16;
          const size_t i = (size_t)r * 1024 + c;
          const float av = acc[mi][ni][j];
          if constexpr (MODE == MZ0) {
            const float z = av * ep.sAi + ep.bias[c];
            wp2(ep.o0h, ep.o0l, i, 0.1f * (z + 0.1f * ep.bias2[c]) * ep.sO);  // 0.1*r1*SIG
            wp2(ep.o1h, ep.o1l, i, 11.f * fmaxf(z, 0.f) * ep.sO);            // r2*SIG
            wp2(ep.o2h, ep.o2l, i, 0.f);                                     // s2 = 0
            ep.of[i] = 0.f;                                                  // s1 = 0
          } else if constexpr (MODE == MVN) {
            const float G = av * ep.sAi;                  // 0.1*r1@Wp + r2@E
            const float r2 = rec2(ep.x0h, ep.x0l, i) * ep.sSi;
            const float v = (r2 + G) * (1.f / 11.f);
            float s2n = 0.f;
            if (ep.dos2) {
              const float s2o = rec2(ep.x2h, ep.x2l, i) * ep.sPi;
              const float vo = (float)ep.x1s[i] * ep.sPi;
              const float qo = rec2(ep.x3h, ep.x3l, i) * ep.sPi;
              s2n = -r2 - s2o - vo + 10.f * fmaxf(-qo, 0.f);
              wp2(ep.o1h, ep.o1l, i, s2n * ep.sO);        // s2(l)
            }
            ep.ov[i] = (f16)(v * ep.sO);                  // v (after reading old v)
            ep.op[i] = (f16)((v + s2n) * ep.sO);          // p = v + s2
          } else if constexpr (MODE == MU || MODE == MUL) {
            const float vW = av * ep.sAi;
            const float r1 = rec2(ep.x0h, ep.x0l, i) * ep.sSi * 10.f;
            const float q = r1 - 0.1f * vW + ep.rf0[i];
            if constexpr (MODE == MU)
              wp2(ep.o0h, ep.o0l, i, q * ep.sO);          // q in-place over r1
            else
              wp2(ep.o0h, ep.o0l, i, -q);                 // logits (scale 1)
          } else if constexpr (MODE == MG) {
            const float gv = av * (1.f / 1024.f);
            ep.of[zoO + i] = gv;
            ep.o0h[zoO + i] = (f16)gv;
          } else if constexpr (MODE == ME) {
            constexpr float C1 = 0.01f / 11.f;
            ep.o0h[zoO + i] = (f16)(32.f * (C1 * C1 * av - C1 * ep.rf0[zoO + i]));
          } else if constexpr (MODE == MWP) {
            const float* Wf = ly == 0 ? ep.w0 : ly == 1 ? ep.w1 : ly == 2 ? ep.w2 : ep.w3;
            ep.o0h[zoO + i] = (f16)(32.f * (Wf[(size_t)c * 1024 + r] + av * (1.f / 1024.f)));  // WpT hi
          }
        }
  }
}

template <int MC>
__global__ void mcprobe() {}  // Mc diagnostic

// x: pad 784->1024, x16, hi plane only
__global__ __launch_bounds__(256) void xstage(const float* __restrict__ src,
                                              f16* __restrict__ h) {
  const size_t i = (size_t)blockIdx.x * 256 + threadIdx.x;
  const int k = (int)(i & 1023);
  const size_t m = i >> 10;
  h[i] = (f16)((k < 784) ? 16.f * src[m * 784 + k] : 0.f);
}

// Win: pad 784->1024, x32 split (z is undamped -> keep Win exact-ish)
__global__ __launch_bounds__(256) void winstage(const float* __restrict__ src,
                                                f16* __restrict__ h, f16* __restrict__ l) {
  const size_t i = (size_t)blockIdx.x * 256 + threadIdx.x;
  const int k = (int)(i & 1023);
  const size_t m = i >> 10;
  const float s = (k < 784) ? 32.f * src[m * 784 + k] : 0.f;
  const f16 hi = (f16)s;
  h[i] = hi;
  l[i] = (f16)(s - (float)hi);
}

// 4 layer weights -> x32 hi planes, direct + transposed
__global__ __launch_bounds__(256) void wstage(const float* __restrict__ W0, const float* __restrict__ W1,
                                              const float* __restrict__ W2, const float* __restrict__ W3,
                                              f16* __restrict__ Wh, f16* __restrict__ WTh) {
  __shared__ float t[32][33];
  const int lz = blockIdx.z;
  const float* W = lz == 0 ? W0 : lz == 1 ? W1 : lz == 2 ? W2 : W3;
  const size_t off = (size_t)lz * 1024 * 1024;
  const int c0 = blockIdx.x * 32, r0 = blockIdx.y * 32;
  const int tx = threadIdx.x, ty = threadIdx.y;
#pragma unroll
  for (int i = ty; i < 32; i += 8) {
    const float v = W[(size_t)(r0 + i) * 1024 + c0 + tx];
    t[i][tx] = v;
    Wh[off + (size_t)(r0 + i) * 1024 + c0 + tx] = (f16)(32.f * v);
  }
  __syncthreads();
#pragma unroll
  for (int i = ty; i < 32; i += 8)
    WTh[off + (size_t)(c0 + i) * 1024 + r0 + tx] = (f16)(32.f * t[tx][i]);
}

// logits = softmax(rec(L) @ Wout^T + bout); one wave per row
__global__ __launch_bounds__(256) void out_softmax(const f16* __restrict__ Lh, const f16* __restrict__ Ll,
                                                   const float* __restrict__ Wout,
                                                   const float* __restrict__ bo,
                                                   float* __restrict__ out) {
  const int row = blockIdx.x * 4 + (threadIdx.x >> 6);
  const int lane = threadIdx.x & 63;
  const size_t rb = (size_t)row * 1024;
  float p[10];
#pragma unroll
  for (int t = 0; t < 10; t++) p[t] = 0.f;
#pragma unroll
  for (int j = 0; j < 4; j++) {
    const int kbase = (j * 64 + lane) * 4;
    const f16x4 hv = *(const f16x4*)(Lh + rb + kbase);
    const f16x4 lv = *(const f16x4*)(Ll + rb + kbase);
    float uv[4];
#pragma unroll
    for (int e = 0; e < 4; e++) uv[e] = (float)hv[e] + (float)lv[e];
#pragma unroll
    for (int t = 0; t < 10; t++) {
      const float4 wv = *(const float4*)(Wout + t * 1024 + kbase);
      p[t] += uv[0] * wv.x + uv[1] * wv.y + uv[2] * wv.z + uv[3] * wv.w;
    }
  }
#pragma unroll
  for (int off = 32; off; off >>= 1)
#pragma unroll
    for (int t = 0; t < 10; t++) p[t] += __shfl_down(p[t], off);
  if (lane == 0) {
    float lg[10], m = -1e30f, s = 0.f;
#pragma unroll
    for (int t = 0; t < 10; t++) { lg[t] = p[t] + bo[t]; m = fmaxf(m, lg[t]); }
#pragma unroll
    for (int t = 0; t < 10; t++) { lg[t] = expf(lg[t] - m); s += lg[t]; }
    const float inv = 1.f / s;
    float* o = out + (size_t)row * 10;
#pragma unroll
    for (int t = 0; t < 10; t++) o[t] = lg[t] * inv;
  }
}

extern "C" void kernel_launch(void* const* d_in, const int* in_sizes, int n_in,
                              void* d_out, int out_size, void* d_ws, size_t ws_size,
                              hipStream_t stream) {
  const float* x = (const float*)d_in[0];
  const float* Win = (const float*)d_in[1];
  const float* bin = (const float*)d_in[2];
  const float* Wgt[4] = {(const float*)d_in[3], (const float*)d_in[5],
                         (const float*)d_in[7], (const float*)d_in[9]};
  const float* bl[4] = {(const float*)d_in[4], (const float*)d_in[6],
                        (const float*)d_in[8], (const float*)d_in[10]};
  const float* Wout = (const float*)d_in[11];
  const float* bout = (const float*)d_in[12];
  float* out = (float*)d_out;

  char* p = (char*)d_ws;
  auto take = [&](size_t n) {
    void* q = (void*)p;
    p += (n + 255) & ~(size_t)255;
    return q;
  };
  const size_t UM = (size_t)1024 * 1024;

  // weights (~36MB)
  f16* Winh = (f16*)take(UM * 2);
  f16* Winl = (f16*)take(UM * 2);
  f16* Wh = (f16*)take(4 * UM * 2);
  f16* WTh = (f16*)take(4 * UM * 2);
  f16* WpTh = (f16*)take(4 * UM * 2);
  f16* E32 = (f16*)take(4 * UM * 2);
  const size_t fixedB = (size_t)(p - (char*)d_ws);

  int Mc = 8192;
  auto actB = [&](int m) {
    size_t a = (size_t)m * 1024 * 24;  // 10 f16 planes + 1 f32
    if (m < 4096) a += 24 * UM;        // dedicated G scratch
    return a;
  };
  while (Mc > 1024 && fixedB + actB(Mc) + 65536 > ws_size) Mc >>= 1;
  if (fixedB + actB(Mc) + 65536 > ws_size) return;
  const size_t CF = (size_t)Mc * 1024;

  f16* P0h = (f16*)take(CF * 2); f16* P0l = (f16*)take(CF * 2);
  f16* Qh = (f16*)take(CF * 2);  f16* Ql = (f16*)take(CF * 2);
  f16* R2h = (f16*)take(CF * 2); f16* R2l = (f16*)take(CF * 2);
  f16* S2h = (f16*)take(CF * 2); f16* S2l = (f16*)take(CF * 2);
  f16* Vh = (f16*)take(CF * 2);
  f16* Ph = (f16*)take(CF * 2);
  float* S1 = (float*)take(CF * 4);
  float* Gf;
  f16* Gh;
  if (Mc >= 4096) {    // alias precompute scratch over act planes (dead then)
    Gf = (float*)P0h;  // 16MB over P0h+P0l
    Gh = (f16*)Qh;     // 8MB over Qh
  } else {
    Gf = (float*)take(4 * UM * 4);
    Gh = (f16*)take(4 * UM * 2);
  }

  switch (Mc) {
    case 8192: mcprobe<8><<<1, 1, 0, stream>>>(); break;
    case 4096: mcprobe<4><<<1, 1, 0, stream>>>(); break;
    case 2048: mcprobe<2><<<1, 1, 0, stream>>>(); break;
    default:   mcprobe<1><<<1, 1, 0, stream>>>(); break;
  }

  // ---- weight precompute (batched over 4 layers via blockIdx.y) ----
  winstage<<<dim3((unsigned)(UM / 256)), 256, 0, stream>>>(Win, Winh, Winl);
  wstage<<<dim3(32, 32, 4), dim3(32, 8), 0, stream>>>(Wgt[0], Wgt[1], Wgt[2], Wgt[3],
                                                      Wh, WTh);
  {  // G = W^T W (hi-only)
    Ep e{};
    e.Ah = WTh; e.Bh = WTh;
    e.zA = UM; e.zB = UM; e.zO = UM;
    e.of = Gf; e.o0h = Gh;
    gk<MG><<<dim3(128, 4), 256, 0, stream>>>(e);
  }
  {  // E32 = 32*(c^2 G^2 - c G)
    Ep e{};
    e.Ah = Gh; e.Bh = Gh; e.zA = UM; e.zB = UM; e.zO = UM;
    e.rf0 = Gf; e.o0h = E32;
    gk<ME><<<dim3(128, 4), 256, 0, stream>>>(e);
  }
  {  // WpT = W^T + E @ W^T (hi plane)
    Ep e{};
    e.Ah = E32; e.Bh = Wh; e.zA = UM; e.zB = UM; e.zO = UM;
    e.w0 = Wgt[0]; e.w1 = Wgt[1]; e.w2 = Wgt[2]; e.w3 = Wgt[3];
    e.o0h = WpTh;
    gk<MWP><<<dim3(128, 4), 256, 0, stream>>>(e);
  }

  const float SIG[5] = {16.f, 2.f, 0.25f, 0.03125f, 1.f};
  const int nch = 8192 / Mc;
  const dim3 gg((unsigned)(Mc / 64) * 8);
  const dim3 gg2((unsigned)(Mc / 64) * 16);

  for (int ch = 0; ch < nch; ++ch) {
    const size_t r0 = (size_t)ch * Mc;
    xstage<<<dim3(Mc * 4), 256, 0, stream>>>(x + r0 * 784, Qh);
    {  // Z0: z = x@Win^T + b_in -> P0 (0.1*r1), R2, S2=0, S1=0
      Ep e{};
      e.Ah = Qh; e.Bh = Winh; e.Bl = Winl;
      e.bias = bin; e.bias2 = bl[0];
      e.o0h = P0h; e.o0l = P0l; e.o1h = R2h; e.o1l = R2l; e.o2h = S2h; e.o2l = S2l;
      e.of = S1; e.sAi = 1.f / 512.f; e.sO = 16.f;
      e.Mh = 1 << 30;
      gk<MZ0><<<gg, 256, 0, stream>>>(e);
    }
    for (int l = 0; l < 4; l++) {
      const size_t lz = (size_t)l * UM;
      const float sl = SIG[l];
      f16 *bCh = (l & 1) ? Qh : P0h, *bCl = (l & 1) ? Ql : P0l;  // r1_l -> q_l
      f16 *bAh = (l & 1) ? P0h : Qh, *bAl = (l & 1) ? P0l : Ql;  // q_{l-1} / r1_{l+1}
      {  // VNEW: v = (r2 + 0.1 r1@Wp + r2@E)/11 -> Vh ; s2(l) -> S2 ; p -> Ph
        Ep e{};
        e.Ah = bCh; e.Bh = WpTh + lz;
        e.A2 = R2h; e.B2 = E32 + lz;
        e.x0h = R2h; e.x0l = R2l;
        e.x1s = Vh;
        e.x2h = S2h; e.x2l = S2l;
        e.x3h = bAh; e.x3l = bAl;
        e.ov = Vh; e.op = Ph; e.o1h = S2h; e.o1l = S2l;
        e.sAi = 1.f / (32.f * sl); e.sSi = 1.f / sl;
        e.sPi = l ? 1.f / SIG[l - 1] : 0.f; e.sO = sl;
        e.dos2 = l ? 1 : 0; e.Mh = 1 << 30;
        gk<MVN><<<gg, 256, 0, stream>>>(e);
      }
      if (l < 3) {
        {  // U: q = 10*(0.1 r1) - 0.1 v@W^T + s1 -> in-place over r1
          Ep e{};
          e.Ah = Vh; e.Bh = Wh + lz;
          e.x0h = bCh; e.x0l = bCl; e.rf0 = S1;
          e.o0h = bCh; e.o0l = bCl;
          e.sAi = 1.f / (32.f * sl); e.sSi = 1.f / sl; e.sO = sl;
          e.Mh = 1 << 30;
          gk<MU><<<gg, 256, 0, stream>>>(e);
        }
        {  // QP: q-half q@W -> r2' ; p-half p@W^T -> s1', r1'
          Ep e{};
          e.Ah = bCh; e.Bh = WTh + lz;
          e.Ch = Ph; e.Dh = Wh + lz;
          e.x0h = bCh; e.x0l = bCl;
          e.x1s = Vh;
          e.x2h = S2h; e.x2l = S2l;
          e.rf0 = S1; e.of = S1;
          e.o0h = R2h; e.o0l = R2l;    // r2'
          e.o1h = bAh; e.o1l = bAl;    // 0.1*r1'
          e.bias2 = bl[l + 1];
          e.sAi = 1.f / (32.f * sl); e.sSi = 1.f / sl; e.sO2 = SIG[l + 1];
          e.Mh = Mc;
          gk<MQP><<<gg2, 256, 0, stream>>>(e);
        }
      } else {  // UL: logits = -(10*(0.1 r1) - 0.1 v@W^T + s1) -> R2 pair (scale 1)
        Ep e{};
        e.Ah = Vh; e.Bh = Wh + lz;
        e.x0h = bCh; e.x0l = bCl; e.rf0 = S1;
        e.o0h = R2h; e.o0l = R2l;
        e.sAi = 1.f / (32.f * sl); e.sSi = 1.f / sl; e.sO = 1.f;
        e.Mh = 1 << 30;
        gk<MUL><<<gg, 256, 0, stream>>>(e);
      }
    }
    out_softmax<<<dim3(Mc / 4), 256, 0, stream>>>(R2h, R2l, Wout, bout, out + r0 * 10);
  }
}

// Round 20
// 1087.072 us; speedup vs baseline: 1.5427x; 1.0049x over previous
//
#include <hip/hip_runtime.h>

typedef _Float16 f16;
typedef _Float16 f16x8 __attribute__((ext_vector_type(8)));
typedef _Float16 f16x4 __attribute__((ext_vector_type(4)));
typedef float f32x4 __attribute__((ext_vector_type(4)));

#define GLD(g, l) __builtin_amdgcn_global_load_lds( \
    (const __attribute__((address_space(1))) void*)(g), \
    (__attribute__((address_space(3))) void*)(l), 16, 0, 0)

enum { MZ0, MVN, MU, MUL, MQP, MG, ME, MWP };

struct Ep {
  const f16 *Ah, *Bh, *Bl;       // primary A (1 plane); B hi (+ lo only for Z0)
  const f16 *A2, *B2;            // VNEW pass 1: r2h @ E32
  const f16 *Ch, *Dh;            // QP p-half: ph @ Wh
  f16 *o0h, *o0l, *o1h, *o1l, *o2h, *o2l;
  f16 *ov, *op;                  // single-plane outs (v, p)
  float* of;
  const f16 *x0h, *x0l, *x2h, *x2l, *x3h, *x3l;
  const f16* x1s;                // single-plane read (v)
  const float* rf0;
  const float *w0, *w1, *w2, *w3;
  const float *bias, *bias2;
  float sAi, sSi, sPi, sO, sO2;
  int Mh, dos2;
  size_t zA, zB, zO;
};

__device__ __forceinline__ float rec2(const f16* h, const f16* l, size_t i) {
  return (float)h[i] + (float)l[i];
}
__device__ __forceinline__ void wp2(f16* h, f16* l, size_t i, float v) {
  const f16 hi = (f16)v;
  h[i] = hi;
  l[i] = (f16)(v - (float)hi);
}

// ---- 8-wide vector helpers (MQP-only, r17-certified) ----
__device__ __forceinline__ void ld_pair8(const f16* h, const f16* l, size_t i, float s, float* o) {
  const f16x8 hv = *(const f16x8*)(h + i);
  const f16x8 lv = *(const f16x8*)(l + i);
#pragma unroll
  for (int e = 0; e < 8; e++) o[e] = ((float)hv[e] + (float)lv[e]) * s;
}
__device__ __forceinline__ void ld_s8(const f16* p, size_t i, float s, float* o) {
  const f16x8 hv = *(const f16x8*)(p + i);
#pragma unroll
  for (int e = 0; e < 8; e++) o[e] = (float)hv[e] * s;
}
__device__ __forceinline__ void ld_f8(const float* p, size_t i, float* o) {
  const float4 a = *(const float4*)(p + i);
  const float4 b = *(const float4*)(p + i + 4);
  o[0] = a.x; o[1] = a.y; o[2] = a.z; o[3] = a.w;
  o[4] = b.x; o[5] = b.y; o[6] = b.z; o[7] = b.w;
}
__device__ __forceinline__ void st_pair8(f16* h, f16* l, size_t i, const float* v, float s) {
  f16x8 hv, lv;
#pragma unroll
  for (int e = 0; e < 8; e++) {
    const float x = v[e] * s;
    const f16 hi = (f16)x;
    hv[e] = hi;
    lv[e] = (f16)(x - (float)hi);
  }
  *(f16x8*)(h + i) = hv;
  *(f16x8*)(l + i) = lv;
}
__device__ __forceinline__ void st_f8(float* p, size_t i, const float* v) {
  *(float4*)(p + i) = make_float4(v[0], v[1], v[2], v[3]);
  *(float4*)(p + i + 4) = make_float4(v[4], v[5], v[6], v[7]);
}

// C = sum_passes A_p @ B_p^T; 64x128 tiles, BK=32, 4 waves (2x2: 2 m-frags x 4 n-frags).
// NP=1 {A@B0}. NP=2: MZ0 {x@Winh, x@Winl}; MVN {r1@Wp, r2@E}. B-lo only for Z0.
// Rotated K-loop (stage next step under MFMA) + chunked XCD swizzle.
// Epilogue: r14-verified scalar path everywhere EXCEPT MQP, which uses a separate
// (non-aliased) [64][132] f32 LDS image + coalesced f16x8/float4 vector state ops.
template <int MODE>
__global__ __launch_bounds__(256, 4) void gk(Ep ep) {
  constexpr bool P2A = (MODE == MVN);  // pass 1 uses its own A (r2@E)
  constexpr int NP = (MODE == MZ0 || MODE == MVN) ? 2 : 1;
  constexpr bool VQ = (MODE == MQP);   // vector-epilogue: MQP only (certified)
  __shared__ f16 SA0[2048] __attribute__((aligned(16)));
  __shared__ f16 SB0[4096] __attribute__((aligned(16)));
  __shared__ f16 SA1[P2A ? 2048 : 16] __attribute__((aligned(16)));
  __shared__ f16 SB1[NP == 2 ? 4096 : 16] __attribute__((aligned(16)));
  __shared__ float EPI[VQ ? 64 * 132 : 4] __attribute__((aligned(16)));
  const int tid = threadIdx.x;
  const int w = tid >> 6, lane = tid & 63;
  const unsigned nb = gridDim.x;
  const unsigned bid = blockIdx.x;
  const unsigned swz = (bid & 7) * (nb >> 3) + (bid >> 3);  // bijective, nb%8==0
  const int tn = (int)(swz & 7) * 128;
  const int tm = (int)(swz >> 3) * 64;
  const int ly = blockIdx.y;
  const size_t zoA = (size_t)ly * ep.zA;
  const size_t zoB = (size_t)ly * ep.zB;
  const size_t zoO = (size_t)ly * ep.zO;

  const bool half2 = (MODE == MQP) && (tm >= ep.Mh);
  const int tmr = half2 ? tm - ep.Mh : tm;

  const f16* pA0 = half2 ? ep.Ch : ep.Ah;
  const f16* pB0 = half2 ? ep.Dh : ep.Bh;

  const int srow = w * 16 + (lane >> 2);  // 0..63
  const int scol = (lane & 3) * 8;
  const size_t aoff = zoA + (size_t)(tmr + srow) * 1024 + scol;
  const size_t boff = zoB + (size_t)(tn + srow) * 1024 + scol;
  const f16* gA0 = pA0 + aoff;
  const f16* gB0 = pB0 + boff;
  const f16* gA1 = P2A ? ep.A2 + aoff : pA0 + aoff;
  const f16* gB1 = (NP == 2) ? ((MODE == MZ0) ? ep.Bl + boff : ep.B2 + boff) : pB0 + boff;

  const int wr = w >> 1, wc = w & 1;
  const int fr = lane & 15;
  const int kb = (lane >> 4) * 8;
  const int ao = (wr * 32 + fr) * 32 + kb;
  const int bo = (wc * 64 + fr) * 32 + kb;

  auto stage = [&](int kt) {
    GLD(gA0 + kt, SA0 + w * 512);
    GLD(gB0 + kt, SB0 + w * 512); GLD(gB0 + kt + 65536, SB0 + 2048 + w * 512);
    if constexpr (P2A) GLD(gA1 + kt, SA1 + w * 512);
    if constexpr (NP == 2) {
      GLD(gB1 + kt, SB1 + w * 512); GLD(gB1 + kt + 65536, SB1 + 2048 + w * 512);
    }
  };

  f32x4 acc[2][4] = {};
  stage(0);

  for (int kt = 0; kt < 1024; kt += 32) {
    __syncthreads();  // staged GLDs complete
    f16x8 a0[2], a1[2], b0[4], b1[4];
#pragma unroll
    for (int i = 0; i < 2; i++) a0[i] = *(const f16x8*)(SA0 + ao + i * 512);
#pragma unroll
    for (int i = 0; i < 4; i++) b0[i] = *(const f16x8*)(SB0 + bo + i * 512);
    if constexpr (P2A) {
#pragma unroll
      for (int i = 0; i < 2; i++) a1[i] = *(const f16x8*)(SA1 + ao + i * 512);
    }
    if constexpr (NP == 2) {
#pragma unroll
      for (int i = 0; i < 4; i++) b1[i] = *(const f16x8*)(SB1 + bo + i * 512);
    }
    __syncthreads();  // all waves done reading LDS
    if (kt < 992) stage(kt + 32);  // next-step loads fly under MFMA

    auto mm = [&](f16x8 (&fa)[2], f16x8 (&fb)[4]) {
#pragma unroll
      for (int mi = 0; mi < 2; mi++)
#pragma unroll
        for (int ni = 0; ni < 4; ni++)
          acc[mi][ni] = __builtin_amdgcn_mfma_f32_16x16x32_f16(fa[mi], fb[ni], acc[mi][ni], 0, 0, 0);
    };
    mm(a0, b0);
    if constexpr (MODE == MZ0) mm(a0, b1);
    if constexpr (MODE == MVN) mm(a1, b1);
  }

  if constexpr (VQ) {
    // MQP vectorized epilogue: separate EPI buffer, unguarded full-tile write
    __syncthreads();
    {
      const int er = wr * 32 + ((lane >> 4) << 2);
      const int ec = wc * 64 + fr;
#pragma unroll
      for (int mi = 0; mi < 2; mi++)
#pragma unroll
        for (int ni = 0; ni < 4; ni++)
#pragma unroll
          for (int j = 0; j < 4; j++)
            EPI[(er + mi * 16 + j) * 132 + ec + ni * 16] = acc[mi][ni][j];
    }
    __syncthreads();
#pragma unroll
    for (int t = 0; t < 4; ++t) {
      const int rl = (tid >> 4) + t * 16;  // 0..63
      const int c8 = (tid & 15) * 8;       // 0..120
      const int r = tmr + rl;
      const int c0 = tn + c8;
      const size_t i = (size_t)r * 1024 + c0;
      float av[8];
      {
        const f32x4 q0 = *(const f32x4*)(EPI + rl * 132 + c8);
        const f32x4 q1 = *(const f32x4*)(EPI + rl * 132 + c8 + 4);
#pragma unroll
        for (int e = 0; e < 4; e++) { av[e] = q0[e]; av[4 + e] = q1[e]; }
      }
      if (!half2) {
        float qq[8], vv[8], s2[8], o[8];
        ld_pair8(ep.x0h, ep.x0l, i, ep.sSi, qq);
        ld_s8(ep.x1s, i, ep.sSi, vv);
        ld_pair8(ep.x2h, ep.x2l, i, ep.sSi, s2);
#pragma unroll
        for (int e = 0; e < 8; e++)
          o[e] = 10.f * vv[e] + 9.f * s2[e] + 10.f * fmaxf(-qq[e], 0.f)
                 - 0.1f * (av[e] * ep.sAi);
        st_pair8(ep.o0h, ep.o0l, i, o, ep.sO2);          // r2'
      } else {
        float qq[8], s1v[8], bib[8], s1o[8], r1n[8];
        ld_pair8(ep.x0h, ep.x0l, i, ep.sSi, qq);
        ld_f8(ep.rf0, i, s1v);
        ld_f8(ep.bias2, c0, bib);
#pragma unroll
        for (int e = 0; e < 8; e++) {
          const float pW = av[e] * ep.sAi;
          s1o[e] = -(qq[e] - s1v[e]) - 0.1f * pW;
          r1n[e] = 0.1f * (0.1f * bib[e] - s1v[e] + 0.1f * pW);
        }
        st_f8(ep.of, i, s1o);                            // s1'
        st_pair8(ep.o1h, ep.o1l, i, r1n, ep.sO2);        // 0.1*r1'
      }
    }
  } else {
    // r14-verified scalar epilogue (all other modes)
    const int er = wr * 32 + ((lane >> 4) << 2);
    const int ec = wc * 64 + fr;
#pragma unroll
    for (int mi = 0; mi < 2; mi++)
#pragma unroll
      for (int ni = 0; ni < 4; ni++)
#pragma unroll
        for (int j = 0; j < 4; j++) {
          const int r = tmr + er + mi * 16 + j;
          const int c = tn + ec + ni * 16;
          const size_t i = (size_t)r * 1024 + c;
          const float av = acc[mi][ni][j];
          if constexpr (MODE == MZ0) {
            const float z = av * ep.sAi + ep.bias[c];
            wp2(ep.o0h, ep.o0l, i, 0.1f * (z + 0.1f * ep.bias2[c]) * ep.sO);  // 0.1*r1*SIG
            wp2(ep.o1h, ep.o1l, i, 11.f * fmaxf(z, 0.f) * ep.sO);            // r2*SIG
            wp2(ep.o2h, ep.o2l, i, 0.f);                                     // s2 = 0
            ep.of[i] = 0.f;                                                  // s1 = 0
          } else if constexpr (MODE == MVN) {
            const float G = av * ep.sAi;                  // 0.1*r1@Wp + r2@E
            const float r2 = rec2(ep.x0h, ep.x0l, i) * ep.sSi;
            const float v = (r2 + G) * (1.f / 11.f);
            float s2n = 0.f;
            if (ep.dos2) {
              const float s2o = rec2(ep.x2h, ep.x2l, i) * ep.sPi;
              const float vo = (float)ep.x1s[i] * ep.sPi;
              const float qo = rec2(ep.x3h, ep.x3l, i) * ep.sPi;
              s2n = -r2 - s2o - vo + 10.f * fmaxf(-qo, 0.f);
              wp2(ep.o1h, ep.o1l, i, s2n * ep.sO);        // s2(l)
            }
            ep.ov[i] = (f16)(v * ep.sO);                  // v (after reading old v)
            ep.op[i] = (f16)((v + s2n) * ep.sO);          // p = v + s2
          } else if constexpr (MODE == MU || MODE == MUL) {
            const float vW = av * ep.sAi;
            const float r1 = rec2(ep.x0h, ep.x0l, i) * ep.sSi * 10.f;
            const float q = r1 - 0.1f * vW + ep.rf0[i];
            if constexpr (MODE == MU)
              wp2(ep.o0h, ep.o0l, i, q * ep.sO);          // q in-place over r1
            else
              wp2(ep.o0h, ep.o0l, i, -q);                 // logits (scale 1)
          } else if constexpr (MODE == MG) {
            const float gv = av * (1.f / 1024.f);
            ep.of[zoO + i] = gv;
            ep.o0h[zoO + i] = (f16)gv;
          } else if constexpr (MODE == ME) {
            constexpr float C1 = 0.01f / 11.f;
            ep.o0h[zoO + i] = (f16)(32.f * (C1 * C1 * av - C1 * ep.rf0[zoO + i]));
          } else if constexpr (MODE == MWP) {
            const float* Wf = ly == 0 ? ep.w0 : ly == 1 ? ep.w1 : ly == 2 ? ep.w2 : ep.w3;
            ep.o0h[zoO + i] = (f16)(32.f * (Wf[(size_t)c * 1024 + r] + av * (1.f / 1024.f)));  // WpT hi
          }
        }
  }
}

template <int MC>
__global__ void mcprobe() {}  // Mc diagnostic

// x: pad 784->1024, x16, hi plane only
__global__ __launch_bounds__(256) void xstage(const float* __restrict__ src,
                                              f16* __restrict__ h) {
  const size_t i = (size_t)blockIdx.x * 256 + threadIdx.x;
  const int k = (int)(i & 1023);
  const size_t m = i >> 10;
  h[i] = (f16)((k < 784) ? 16.f * src[m * 784 + k] : 0.f);
}

// Win: pad 784->1024, x32 split (z is undamped -> keep Win exact-ish)
__global__ __launch_bounds__(256) void winstage(const float* __restrict__ src,
                                                f16* __restrict__ h, f16* __restrict__ l) {
  const size_t i = (size_t)blockIdx.x * 256 + threadIdx.x;
  const int k = (int)(i & 1023);
  const size_t m = i >> 10;
  const float s = (k < 784) ? 32.f * src[m * 784 + k] : 0.f;
  const f16 hi = (f16)s;
  h[i] = hi;
  l[i] = (f16)(s - (float)hi);
}

// 4 layer weights -> x32 hi planes, direct + transposed
__global__ __launch_bounds__(256) void wstage(const float* __restrict__ W0, const float* __restrict__ W1,
                                              const float* __restrict__ W2, const float* __restrict__ W3,
                                              f16* __restrict__ Wh, f16* __restrict__ WTh) {
  __shared__ float t[32][33];
  const int lz = blockIdx.z;
  const float* W = lz == 0 ? W0 : lz == 1 ? W1 : lz == 2 ? W2 : W3;
  const size_t off = (size_t)lz * 1024 * 1024;
  const int c0 = blockIdx.x * 32, r0 = blockIdx.y * 32;
  const int tx = threadIdx.x, ty = threadIdx.y;
#pragma unroll
  for (int i = ty; i < 32; i += 8) {
    const float v = W[(size_t)(r0 + i) * 1024 + c0 + tx];
    t[i][tx] = v;
    Wh[off + (size_t)(r0 + i) * 1024 + c0 + tx] = (f16)(32.f * v);
  }
  __syncthreads();
#pragma unroll
  for (int i = ty; i < 32; i += 8)
    WTh[off + (size_t)(c0 + i) * 1024 + r0 + tx] = (f16)(32.f * t[tx][i]);
}

// logits = softmax(rec(L) @ Wout^T + bout); one wave per row
__global__ __launch_bounds__(256) void out_softmax(const f16* __restrict__ Lh, const f16* __restrict__ Ll,
                                                   const float* __restrict__ Wout,
                                                   const float* __restrict__ bo,
                                                   float* __restrict__ out) {
  const int row = blockIdx.x * 4 + (threadIdx.x >> 6);
  const int lane = threadIdx.x & 63;
  const size_t rb = (size_t)row * 1024;
  float p[10];
#pragma unroll
  for (int t = 0; t < 10; t++) p[t] = 0.f;
#pragma unroll
  for (int j = 0; j < 4; j++) {
    const int kbase = (j * 64 + lane) * 4;
    const f16x4 hv = *(const f16x4*)(Lh + rb + kbase);
    const f16x4 lv = *(const f16x4*)(Ll + rb + kbase);
    float uv[4];
#pragma unroll
    for (int e = 0; e < 4; e++) uv[e] = (float)hv[e] + (float)lv[e];
#pragma unroll
    for (int t = 0; t < 10; t++) {
      const float4 wv = *(const float4*)(Wout + t * 1024 + kbase);
      p[t] += uv[0] * wv.x + uv[1] * wv.y + uv[2] * wv.z + uv[3] * wv.w;
    }
  }
#pragma unroll
  for (int off = 32; off; off >>= 1)
#pragma unroll
    for (int t = 0; t < 10; t++) p[t] += __shfl_down(p[t], off);
  if (lane == 0) {
    float lg[10], m = -1e30f, s = 0.f;
#pragma unroll
    for (int t = 0; t < 10; t++) { lg[t] = p[t] + bo[t]; m = fmaxf(m, lg[t]); }
#pragma unroll
    for (int t = 0; t < 10; t++) { lg[t] = expf(lg[t] - m); s += lg[t]; }
    const float inv = 1.f / s;
    float* o = out + (size_t)row * 10;
#pragma unroll
    for (int t = 0; t < 10; t++) o[t] = lg[t] * inv;
  }
}

extern "C" void kernel_launch(void* const* d_in, const int* in_sizes, int n_in,
                              void* d_out, int out_size, void* d_ws, size_t ws_size,
                              hipStream_t stream) {
  const float* x = (const float*)d_in[0];
  const float* Win = (const float*)d_in[1];
  const float* bin = (const float*)d_in[2];
  const float* Wgt[4] = {(const float*)d_in[3], (const float*)d_in[5],
                         (const float*)d_in[7], (const float*)d_in[9]};
  const float* bl[4] = {(const float*)d_in[4], (const float*)d_in[6],
                        (const float*)d_in[8], (const float*)d_in[10]};
  const float* Wout = (const float*)d_in[11];
  const float* bout = (const float*)d_in[12];
  float* out = (float*)d_out;

  char* p = (char*)d_ws;
  auto take = [&](size_t n) {
    void* q = (void*)p;
    p += (n + 255) & ~(size_t)255;
    return q;
  };
  const size_t UM = (size_t)1024 * 1024;

  // weights (~36MB)
  f16* Winh = (f16*)take(UM * 2);
  f16* Winl = (f16*)take(UM * 2);
  f16* Wh = (f16*)take(4 * UM * 2);
  f16* WTh = (f16*)take(4 * UM * 2);
  f16* WpTh = (f16*)take(4 * UM * 2);
  f16* E32 = (f16*)take(4 * UM * 2);
  const size_t fixedB = (size_t)(p - (char*)d_ws);

  int Mc = 8192;
  auto actB = [&](int m) {
    size_t a = (size_t)m * 1024 * 24;  // 10 f16 planes + 1 f32
    if (m < 4096) a += 24 * UM;        // dedicated G scratch
    return a;
  };
  while (Mc > 1024 && fixedB + actB(Mc) + 65536 > ws_size) Mc >>= 1;
  if (fixedB + actB(Mc) + 65536 > ws_size) return;
  const size_t CF = (size_t)Mc * 1024;

  f16* P0h = (f16*)take(CF * 2); f16* P0l = (f16*)take(CF * 2);
  f16* Qh = (f16*)take(CF * 2);  f16* Ql = (f16*)take(CF * 2);
  f16* R2h = (f16*)take(CF * 2); f16* R2l = (f16*)take(CF * 2);
  f16* S2h = (f16*)take(CF * 2); f16* S2l = (f16*)take(CF * 2);
  f16* Vh = (f16*)take(CF * 2);
  f16* Ph = (f16*)take(CF * 2);
  float* S1 = (float*)take(CF * 4);
  float* Gf;
  f16* Gh;
  if (Mc >= 4096) {    // alias precompute scratch over act planes (dead then)
    Gf = (float*)P0h;  // 16MB over P0h+P0l
    Gh = (f16*)Qh;     // 8MB over Qh
  } else {
    Gf = (float*)take(4 * UM * 4);
    Gh = (f16*)take(4 * UM * 2);
  }

  switch (Mc) {
    case 8192: mcprobe<8><<<1, 1, 0, stream>>>(); break;
    case 4096: mcprobe<4><<<1, 1, 0, stream>>>(); break;
    case 2048: mcprobe<2><<<1, 1, 0, stream>>>(); break;
    default:   mcprobe<1><<<1, 1, 0, stream>>>(); break;
  }

  // ---- weight precompute (batched over 4 layers via blockIdx.y) ----
  winstage<<<dim3((unsigned)(UM / 256)), 256, 0, stream>>>(Win, Winh, Winl);
  wstage<<<dim3(32, 32, 4), dim3(32, 8), 0, stream>>>(Wgt[0], Wgt[1], Wgt[2], Wgt[3],
                                                      Wh, WTh);
  {  // G = W^T W (hi-only)
    Ep e{};
    e.Ah = WTh; e.Bh = WTh;
    e.zA = UM; e.zB = UM; e.zO = UM;
    e.of = Gf; e.o0h = Gh;
    gk<MG><<<dim3(128, 4), 256, 0, stream>>>(e);
  }
  {  // E32 = 32*(c^2 G^2 - c G)
    Ep e{};
    e.Ah = Gh; e.Bh = Gh; e.zA = UM; e.zB = UM; e.zO = UM;
    e.rf0 = Gf; e.o0h = E32;
    gk<ME><<<dim3(128, 4), 256, 0, stream>>>(e);
  }
  {  // WpT = W^T + E @ W^T (hi plane)
    Ep e{};
    e.Ah = E32; e.Bh = Wh; e.zA = UM; e.zB = UM; e.zO = UM;
    e.w0 = Wgt[0]; e.w1 = Wgt[1]; e.w2 = Wgt[2]; e.w3 = Wgt[3];
    e.o0h = WpTh;
    gk<MWP><<<dim3(128, 4), 256, 0, stream>>>(e);
  }

  const float SIG[5] = {16.f, 2.f, 0.25f, 0.03125f, 1.f};
  const int nch = 8192 / Mc;
  const dim3 gg((unsigned)(Mc / 64) * 8);
  const dim3 gg2((unsigned)(Mc / 64) * 16);

  for (int ch = 0; ch < nch; ++ch) {
    const size_t r0 = (size_t)ch * Mc;
    xstage<<<dim3(Mc * 4), 256, 0, stream>>>(x + r0 * 784, Qh);
    {  // Z0: z = x@Win^T + b_in -> P0 (0.1*r1), R2, S2=0, S1=0
      Ep e{};
      e.Ah = Qh; e.Bh = Winh; e.Bl = Winl;
      e.bias = bin; e.bias2 = bl[0];
      e.o0h = P0h; e.o0l = P0l; e.o1h = R2h; e.o1l = R2l; e.o2h = S2h; e.o2l = S2l;
      e.of = S1; e.sAi = 1.f / 512.f; e.sO = 16.f;
      e.Mh = 1 << 30;
      gk<MZ0><<<gg, 256, 0, stream>>>(e);
    }
    for (int l = 0; l < 4; l++) {
      const size_t lz = (size_t)l * UM;
      const float sl = SIG[l];
      f16 *bCh = (l & 1) ? Qh : P0h, *bCl = (l & 1) ? Ql : P0l;  // r1_l -> q_l
      f16 *bAh = (l & 1) ? P0h : Qh, *bAl = (l & 1) ? P0l : Ql;  // q_{l-1} / r1_{l+1}
      {  // VNEW: v = (r2 + 0.1 r1@Wp + r2@E)/11 -> Vh ; s2(l) -> S2 ; p -> Ph
        Ep e{};
        e.Ah = bCh; e.Bh = WpTh + lz;
        e.A2 = R2h; e.B2 = E32 + lz;
        e.x0h = R2h; e.x0l = R2l;
        e.x1s = Vh;
        e.x2h = S2h; e.x2l = S2l;
        e.x3h = bAh; e.x3l = bAl;
        e.ov = Vh; e.op = Ph; e.o1h = S2h; e.o1l = S2l;
        e.sAi = 1.f / (32.f * sl); e.sSi = 1.f / sl;
        e.sPi = l ? 1.f / SIG[l - 1] : 0.f; e.sO = sl;
        e.dos2 = l ? 1 : 0; e.Mh = 1 << 30;
        gk<MVN><<<gg, 256, 0, stream>>>(e);
      }
      if (l < 3) {
        {  // U: q = 10*(0.1 r1) - 0.1 v@W^T + s1 -> in-place over r1
          Ep e{};
          e.Ah = Vh; e.Bh = Wh + lz;
          e.x0h = bCh; e.x0l = bCl; e.rf0 = S1;
          e.o0h = bCh; e.o0l = bCl;
          e.sAi = 1.f / (32.f * sl); e.sSi = 1.f / sl; e.sO = sl;
          e.Mh = 1 << 30;
          gk<MU><<<gg, 256, 0, stream>>>(e);
        }
        {  // QP: q-half q@W -> r2' ; p-half p@W^T -> s1', r1'
          Ep e{};
          e.Ah = bCh; e.Bh = WTh + lz;
          e.Ch = Ph; e.Dh = Wh + lz;
          e.x0h = bCh; e.x0l = bCl;
          e.x1s = Vh;
          e.x2h = S2h; e.x2l = S2l;
          e.rf0 = S1; e.of = S1;
          e.o0h = R2h; e.o0l = R2l;    // r2'
          e.o1h = bAh; e.o1l = bAl;    // 0.1*r1'
          e.bias2 = bl[l + 1];
          e.sAi = 1.f / (32.f * sl); e.sSi = 1.f / sl; e.sO2 = SIG[l + 1];
          e.Mh = Mc;
          gk<MQP><<<gg2, 256, 0, stream>>>(e);
        }
      } else {  // UL: logits = -(10*(0.1 r1) - 0.1 v@W^T + s1) -> R2 pair (scale 1)
        Ep e{};
        e.Ah = Vh; e.Bh = Wh + lz;
        e.x0h = bCh; e.x0l = bCl; e.rf0 = S1;
        e.o0h = R2h; e.o0l = R2l;
        e.sAi = 1.f / (32.f * sl); e.sSi = 1.f / sl; e.sO = 1.f;
        e.Mh = 1 << 30;
        gk<MUL><<<gg, 256, 0, stream>>>(e);
      }
    }
    out_softmax<<<dim3(Mc / 4), 256, 0, stream>>>(R2h, R2l, Wout, bout, out + r0 * 10);
  }
}